// Round 1
// baseline (1516.177 us; speedup 1.0000x reference)
//
#include <hip/hip_runtime.h>
#include <hip/hip_bf16.h>
#include <math.h>

// Problem constants (B=1, S=4096, D=1024, H=16, hd=64)
#define S_LEN 4096
#define D_MODEL 1024
#define NHEAD 16
#define HD 64
#define NQB (S_LEN / 64)   // 64 q-blocks of 64 rows

// ---------------------------------------------------------------------------
// GEMM: C[m,n] = sum_k A[m,k] * B[n,k]   (B given row-major N x K, i.e. B^T)
// BM=128, BN=64, BK=16, 256 threads, 8x4 micro-tile.
// DO_ROPE: apply rotary embedding to the output tile (cols are one head since
// BN==64 and head dim==64; bn is a multiple of 64).
// ---------------------------------------------------------------------------
template<int DO_ROPE>
__global__ __launch_bounds__(256)
void gemm_bt(const float* __restrict__ A, const float* __restrict__ B,
             float* __restrict__ C, const int* __restrict__ pos,
             int M, int N, int K) {
  __shared__ float As[16][132];  // k-major, pad 4 (132*4B = 16B aligned rows)
  __shared__ float Bs[16][68];

  const int tid = threadIdx.x;
  const int tx = tid & 15;        // 0..15 -> output cols tx*4..tx*4+3
  const int ty = tid >> 4;        // 0..15 -> output rows ty*8..ty*8+7
  const int bm = blockIdx.y * 128;
  const int bn = blockIdx.x * 64;

  float acc[8][4];
#pragma unroll
  for (int i = 0; i < 8; ++i)
#pragma unroll
    for (int j = 0; j < 4; ++j) acc[i][j] = 0.0f;

  const float* Ap = A + (size_t)bm * K;
  const float* Bp = B + (size_t)bn * K;

  const int r0 = tid >> 2;            // 0..63
  const int q0 = (tid & 3) << 2;      // 0,4,8,12

  for (int k0 = 0; k0 < K; k0 += 16) {
    float4 a0 = *(const float4*)(Ap + (size_t)r0 * K + k0 + q0);
    float4 a1 = *(const float4*)(Ap + (size_t)(r0 + 64) * K + k0 + q0);
    float4 b0 = *(const float4*)(Bp + (size_t)r0 * K + k0 + q0);

    __syncthreads();   // previous iteration's reads done
    As[q0 + 0][r0] = a0.x; As[q0 + 1][r0] = a0.y;
    As[q0 + 2][r0] = a0.z; As[q0 + 3][r0] = a0.w;
    As[q0 + 0][r0 + 64] = a1.x; As[q0 + 1][r0 + 64] = a1.y;
    As[q0 + 2][r0 + 64] = a1.z; As[q0 + 3][r0 + 64] = a1.w;
    Bs[q0 + 0][r0] = b0.x; Bs[q0 + 1][r0] = b0.y;
    Bs[q0 + 2][r0] = b0.z; Bs[q0 + 3][r0] = b0.w;
    __syncthreads();

#pragma unroll
    for (int kk = 0; kk < 16; ++kk) {
      float4 aa0 = *(const float4*)&As[kk][ty * 8];
      float4 aa1 = *(const float4*)&As[kk][ty * 8 + 4];
      float4 bb  = *(const float4*)&Bs[kk][tx * 4];
#define GEMM_FMA_ROW(r, av)                                   \
      acc[r][0] += (av) * bb.x; acc[r][1] += (av) * bb.y;     \
      acc[r][2] += (av) * bb.z; acc[r][3] += (av) * bb.w;
      GEMM_FMA_ROW(0, aa0.x) GEMM_FMA_ROW(1, aa0.y)
      GEMM_FMA_ROW(2, aa0.z) GEMM_FMA_ROW(3, aa0.w)
      GEMM_FMA_ROW(4, aa1.x) GEMM_FMA_ROW(5, aa1.y)
      GEMM_FMA_ROW(6, aa1.z) GEMM_FMA_ROW(7, aa1.w)
#undef GEMM_FMA_ROW
    }
  }

  if constexpr (DO_ROPE != 0) {
    // within-head channel = tx*4 + j (bn is a multiple of 64). Pair indices:
    // (j=0,1) -> tx*2 ; (j=2,3) -> tx*2+1. freq = 1/theta^(2*idx/64).
    const int idx0 = tx * 2, idx1 = tx * 2 + 1;
    const float fr0 = 1.0f / powf(10000.0f, (float)(2 * idx0) * (1.0f / 64.0f));
    const float fr1 = 1.0f / powf(10000.0f, (float)(2 * idx1) * (1.0f / 64.0f));
#pragma unroll
    for (int i = 0; i < 8; ++i) {
      const int srow = bm + ty * 8 + i;
      const float pp = (float)pos[srow];
      float s0, c0, s1, c1;
      sincosf(pp * fr0, &s0, &c0);
      sincosf(pp * fr1, &s1, &c1);
      float e = acc[i][0], o = acc[i][1];
      acc[i][0] = e * c0 - o * s0;
      acc[i][1] = e * s0 + o * c0;
      e = acc[i][2]; o = acc[i][3];
      acc[i][2] = e * c1 - o * s1;
      acc[i][3] = e * s1 + o * c1;
    }
  }

#pragma unroll
  for (int i = 0; i < 8; ++i) {
    *(float4*)(C + (size_t)(bm + ty * 8 + i) * N + bn + tx * 4) =
        make_float4(acc[i][0], acc[i][1], acc[i][2], acc[i][3]);
  }
}

// ---------------------------------------------------------------------------
// Flash attention, fp32. One workgroup handles head h and TWO q-blocks
// (pairId, 63-pairId) -> balanced causal work (65 k-tiles per block).
// 64x64 tiles; 256 threads; thread (ty,tx) owns a 4x4 sub-tile.
// LDS tiles are XOR-swizzled on the float4-chunk index: chunk' = chunk ^
// ((row>>2)&15). 4 tiles * 16 KiB = 64 KiB, all compute accesses conflict-free.
// ---------------------------------------------------------------------------
#define DOT4(a, b) ((a).x*(b).x + (a).y*(b).y + (a).z*(b).z + (a).w*(b).w)

__global__ __launch_bounds__(256)
void attn_kernel(const float* __restrict__ Q, const float* __restrict__ Kg,
                 const float* __restrict__ Vg, float* __restrict__ Og) {
  __shared__ float Qs[64][64];
  __shared__ float Ks[64][64];
  __shared__ float Vs[64][64];
  __shared__ float Ps[64][64];

  const int tid = threadIdx.x;
  const int tx = tid & 15, ty = tid >> 4;
  const int h = blockIdx.y;
  const int pairId = blockIdx.x;   // 0..31

  for (int which = 0; which < 2; ++which) {
    const int qb = (which == 0) ? pairId : (NQB - 1 - pairId);

    __syncthreads();  // previous q-block fully done with LDS
    // stage Q tile (scaled by 1/sqrt(64))
#pragma unroll
    for (int l = 0; l < 4; ++l) {
      int c = tid + l * 256;
      int row = c >> 4, cc = c & 15;
      float4 v = *(const float4*)(Q + (size_t)(qb * 64 + row) * D_MODEL + h * HD + cc * 4);
      v.x *= 0.125f; v.y *= 0.125f; v.z *= 0.125f; v.w *= 0.125f;
      *(float4*)&Qs[row][((cc ^ ((row >> 2) & 15)) << 2)] = v;
    }

    float m_[4], l_[4], accO[4][4];
#pragma unroll
    for (int i = 0; i < 4; ++i) {
      m_[i] = -1e30f; l_[i] = 0.0f;
#pragma unroll
      for (int j = 0; j < 4; ++j) accO[i][j] = 0.0f;
    }

    for (int kb = 0; kb <= qb; ++kb) {
      __syncthreads();  // prior GEMM2 done with Ks/Vs/Ps
#pragma unroll
      for (int l = 0; l < 4; ++l) {
        int c = tid + l * 256;
        int row = c >> 4, cc = c & 15;
        int sc = (cc ^ ((row >> 2) & 15)) << 2;
        *(float4*)&Ks[row][sc] =
            *(const float4*)(Kg + (size_t)(kb * 64 + row) * D_MODEL + h * HD + cc * 4);
        *(float4*)&Vs[row][sc] =
            *(const float4*)(Vg + (size_t)(kb * 64 + row) * D_MODEL + h * HD + cc * 4);
      }
      __syncthreads();

      // GEMM1: s[i][j] = sum_c Qs[ty*4+i][c] * Ks[tx*4+j][c]
      float s[4][4];
#pragma unroll
      for (int i = 0; i < 4; ++i)
#pragma unroll
        for (int j = 0; j < 4; ++j) s[i][j] = 0.0f;

#pragma unroll
      for (int c4 = 0; c4 < 16; ++c4) {
        float4 qa[4], ka[4];
#pragma unroll
        for (int i = 0; i < 4; ++i)
          qa[i] = *(const float4*)&Qs[ty * 4 + i][((c4 ^ ty) << 2)];
#pragma unroll
        for (int j = 0; j < 4; ++j)
          ka[j] = *(const float4*)&Ks[tx * 4 + j][((c4 ^ tx) << 2)];
#pragma unroll
        for (int i = 0; i < 4; ++i) {
          s[i][0] += DOT4(qa[i], ka[0]);
          s[i][1] += DOT4(qa[i], ka[1]);
          s[i][2] += DOT4(qa[i], ka[2]);
          s[i][3] += DOT4(qa[i], ka[3]);
        }
      }

      if (kb == qb) {  // causal mask on the diagonal tile
#pragma unroll
        for (int i = 0; i < 4; ++i)
#pragma unroll
          for (int j = 0; j < 4; ++j)
            if (tx * 4 + j > ty * 4 + i) s[i][j] = -1e30f;
      }

      // online softmax (rows split across the 16 tx lanes)
#pragma unroll
      for (int i = 0; i < 4; ++i) {
        float tm = fmaxf(fmaxf(s[i][0], s[i][1]), fmaxf(s[i][2], s[i][3]));
        tm = fmaxf(tm, __shfl_xor(tm, 1));
        tm = fmaxf(tm, __shfl_xor(tm, 2));
        tm = fmaxf(tm, __shfl_xor(tm, 4));
        tm = fmaxf(tm, __shfl_xor(tm, 8));
        const float mn = fmaxf(m_[i], tm);
        const float sc = expf(m_[i] - mn);
        m_[i] = mn;
        float p0 = expf(s[i][0] - mn), p1 = expf(s[i][1] - mn);
        float p2 = expf(s[i][2] - mn), p3 = expf(s[i][3] - mn);
        float rs = p0 + p1 + p2 + p3;
        rs += __shfl_xor(rs, 1);
        rs += __shfl_xor(rs, 2);
        rs += __shfl_xor(rs, 4);
        rs += __shfl_xor(rs, 8);
        l_[i] = l_[i] * sc + rs;
        accO[i][0] *= sc; accO[i][1] *= sc; accO[i][2] *= sc; accO[i][3] *= sc;
        s[i][0] = p0; s[i][1] = p1; s[i][2] = p2; s[i][3] = p3;
      }

      // write P tile (row ty*4+i, logical chunk tx -> swizzled pos tx^ty)
#pragma unroll
      for (int i = 0; i < 4; ++i) {
        *(float4*)&Ps[ty * 4 + i][((tx ^ ty) << 2)] =
            make_float4(s[i][0], s[i][1], s[i][2], s[i][3]);
      }
      __syncthreads();

      // GEMM2: accO[i][j] += sum_k2 Ps[ty*4+i][k2] * Vs[k2][tx*4+j]
#pragma unroll
      for (int k4 = 0; k4 < 16; ++k4) {
        float4 pa[4], va[4];
#pragma unroll
        for (int i = 0; i < 4; ++i)
          pa[i] = *(const float4*)&Ps[ty * 4 + i][((k4 ^ ty) << 2)];
#pragma unroll
        for (int t = 0; t < 4; ++t)
          va[t] = *(const float4*)&Vs[k4 * 4 + t][((tx ^ k4) << 2)];
#pragma unroll
        for (int i = 0; i < 4; ++i) {
          accO[i][0] += pa[i].x*va[0].x + pa[i].y*va[1].x + pa[i].z*va[2].x + pa[i].w*va[3].x;
          accO[i][1] += pa[i].x*va[0].y + pa[i].y*va[1].y + pa[i].z*va[2].y + pa[i].w*va[3].y;
          accO[i][2] += pa[i].x*va[0].z + pa[i].y*va[1].z + pa[i].z*va[2].z + pa[i].w*va[3].z;
          accO[i][3] += pa[i].x*va[0].w + pa[i].y*va[1].w + pa[i].z*va[2].w + pa[i].w*va[3].w;
        }
      }
    }  // kb

    // epilogue: normalize and store (O laid out [S][D], head h at cols h*64)
#pragma unroll
    for (int i = 0; i < 4; ++i) {
      const float inv = 1.0f / l_[i];
      *(float4*)(Og + (size_t)(qb * 64 + ty * 4 + i) * D_MODEL + h * HD + tx * 4) =
          make_float4(accO[i][0] * inv, accO[i][1] * inv,
                      accO[i][2] * inv, accO[i][3] * inv);
    }
  }  // which
}

// ---------------------------------------------------------------------------
extern "C" void kernel_launch(void* const* d_in, const int* in_sizes, int n_in,
                              void* d_out, int out_size, void* d_ws, size_t ws_size,
                              hipStream_t stream) {
  const float* x   = (const float*)d_in[0];
  const int*   pos = (const int*)d_in[1];
  const float* Wq  = (const float*)d_in[2];
  const float* Wk  = (const float*)d_in[3];
  const float* Wv  = (const float*)d_in[4];
  const float* Wo  = (const float*)d_in[5];
  float* out = (float*)d_out;

  const size_t SD = (size_t)S_LEN * D_MODEL;
  float* Qb = (float*)d_ws;
  float* Kb = Qb + SD;
  float* Vb = Kb + SD;
  float* Ob = Vb + SD;   // 64 MB total fp32 scratch

  dim3 blk(256);
  dim3 gg(D_MODEL / 64, S_LEN / 128);  // (16, 32)

  hipLaunchKernelGGL((gemm_bt<1>), gg, blk, 0, stream, x, Wq, Qb, pos,
                     S_LEN, D_MODEL, D_MODEL);
  hipLaunchKernelGGL((gemm_bt<1>), gg, blk, 0, stream, x, Wk, Kb, pos,
                     S_LEN, D_MODEL, D_MODEL);
  hipLaunchKernelGGL((gemm_bt<0>), gg, blk, 0, stream, x, Wv, Vb, nullptr,
                     S_LEN, D_MODEL, D_MODEL);

  hipLaunchKernelGGL(attn_kernel, dim3(32, NHEAD), blk, 0, stream, Qb, Kb, Vb, Ob);

  hipLaunchKernelGGL((gemm_bt<0>), gg, blk, 0, stream, Ob, Wo, out, nullptr,
                     S_LEN, D_MODEL, D_MODEL);
}

// Round 3
// 835.302 us; speedup vs baseline: 1.8151x; 1.8151x over previous
//
#include <hip/hip_runtime.h>
#include <hip/hip_bf16.h>
#include <math.h>

// Problem constants (B=1, S=4096, D=1024, H=16, hd=64)
#define S_LEN 4096
#define D_MODEL 1024
#define NHEAD 16
#define HD 64

typedef short bf16x8 __attribute__((ext_vector_type(8)));
typedef float f32x16 __attribute__((ext_vector_type(16)));

static __device__ __forceinline__ unsigned pk2(float lo, float hi) {
  __hip_bfloat162 h = __float22bfloat162_rn(make_float2(lo, hi));
  return *reinterpret_cast<unsigned*>(&h);
}
static __device__ __forceinline__ unsigned short bf1(float x) {
  __hip_bfloat16 h = __float2bfloat16(x);
  return *reinterpret_cast<unsigned short*>(&h);
}

// ---------------------------------------------------------------------------
// fp32 GEMM (round-1 proven): C[m,n] = sum_k A[m,k] * B[n,k]
// BM=128, BN=64, BK=16, 256 threads, 8x4 micro-tile.
// ---------------------------------------------------------------------------
template<int DO_ROPE>
__global__ __launch_bounds__(256)
void gemm_bt(const float* __restrict__ A, const float* __restrict__ B,
             float* __restrict__ C, const int* __restrict__ pos,
             int M, int N, int K) {
  __shared__ float As[16][132];
  __shared__ float Bs[16][68];

  const int tid = threadIdx.x;
  const int tx = tid & 15;
  const int ty = tid >> 4;
  const int bm = blockIdx.y * 128;
  const int bn = blockIdx.x * 64;

  float acc[8][4];
#pragma unroll
  for (int i = 0; i < 8; ++i)
#pragma unroll
    for (int j = 0; j < 4; ++j) acc[i][j] = 0.0f;

  const float* Ap = A + (size_t)bm * K;
  const float* Bp = B + (size_t)bn * K;

  const int r0 = tid >> 2;
  const int q0 = (tid & 3) << 2;

  for (int k0 = 0; k0 < K; k0 += 16) {
    float4 a0 = *(const float4*)(Ap + (size_t)r0 * K + k0 + q0);
    float4 a1 = *(const float4*)(Ap + (size_t)(r0 + 64) * K + k0 + q0);
    float4 b0 = *(const float4*)(Bp + (size_t)r0 * K + k0 + q0);

    __syncthreads();
    As[q0 + 0][r0] = a0.x; As[q0 + 1][r0] = a0.y;
    As[q0 + 2][r0] = a0.z; As[q0 + 3][r0] = a0.w;
    As[q0 + 0][r0 + 64] = a1.x; As[q0 + 1][r0 + 64] = a1.y;
    As[q0 + 2][r0 + 64] = a1.z; As[q0 + 3][r0 + 64] = a1.w;
    Bs[q0 + 0][r0] = b0.x; Bs[q0 + 1][r0] = b0.y;
    Bs[q0 + 2][r0] = b0.z; Bs[q0 + 3][r0] = b0.w;
    __syncthreads();

#pragma unroll
    for (int kk = 0; kk < 16; ++kk) {
      float4 aa0 = *(const float4*)&As[kk][ty * 8];
      float4 aa1 = *(const float4*)&As[kk][ty * 8 + 4];
      float4 bb  = *(const float4*)&Bs[kk][tx * 4];
#define GEMM_FMA_ROW(r, av)                                   \
      acc[r][0] += (av) * bb.x; acc[r][1] += (av) * bb.y;     \
      acc[r][2] += (av) * bb.z; acc[r][3] += (av) * bb.w;
      GEMM_FMA_ROW(0, aa0.x) GEMM_FMA_ROW(1, aa0.y)
      GEMM_FMA_ROW(2, aa0.z) GEMM_FMA_ROW(3, aa0.w)
      GEMM_FMA_ROW(4, aa1.x) GEMM_FMA_ROW(5, aa1.y)
      GEMM_FMA_ROW(6, aa1.z) GEMM_FMA_ROW(7, aa1.w)
#undef GEMM_FMA_ROW
    }
  }

  if constexpr (DO_ROPE != 0) {
    const int idx0 = tx * 2, idx1 = tx * 2 + 1;
    const float fr0 = 1.0f / powf(10000.0f, (float)(2 * idx0) * (1.0f / 64.0f));
    const float fr1 = 1.0f / powf(10000.0f, (float)(2 * idx1) * (1.0f / 64.0f));
#pragma unroll
    for (int i = 0; i < 8; ++i) {
      const int srow = bm + ty * 8 + i;
      const float pp = (float)pos[srow];
      float s0, c0, s1, c1;
      sincosf(pp * fr0, &s0, &c0);
      sincosf(pp * fr1, &s1, &c1);
      float e = acc[i][0], o = acc[i][1];
      acc[i][0] = e * c0 - o * s0;
      acc[i][1] = e * s0 + o * c0;
      e = acc[i][2]; o = acc[i][3];
      acc[i][2] = e * c1 - o * s1;
      acc[i][3] = e * s1 + o * c1;
    }
  }

#pragma unroll
  for (int i = 0; i < 8; ++i) {
    *(float4*)(C + (size_t)(bm + ty * 8 + i) * N + bn + tx * 4) =
        make_float4(acc[i][0], acc[i][1], acc[i][2], acc[i][3]);
  }
}

// ---------------------------------------------------------------------------
// bf16 MFMA flash attention (swapped-QK^T, m214 structure).
// Workgroup = 4 waves, Q-block = 128 rows (32 q-rows/wave). K/V tiles of 64.
// All LDS tiles XOR-swizzled: byte ^= (row&7)<<4.
// S^T = mfma(K, Q)  -> lane owns q = lane&31, k spread over 16 regs.
// P packed to bf16 via cvt_pk pairs + v_permlane32_swap_b32 -> PV B-operand.
// O^T accumulated in regs; epilogue transposes through LDS.
// Alignment note: wave q-origin and key subtiles are both 32-aligned, so a
// processed subtile always has ks <= q_wave_start -> every lane has >=1
// unmasked key -> softmax never sees a fully-masked row.
// ---------------------------------------------------------------------------
union __align__(16) AttnSmem {
  unsigned short q[128 * 64];                                  // 16 KB
  struct { unsigned short k[64 * 64]; unsigned short vt[64 * 64]; } kv;  // 16 KB
  float oep[4][32][68];                                        // 34 KB
};

__global__ __launch_bounds__(256)
void attn_mfma(const float* __restrict__ Qg, const float* __restrict__ Kg,
               const float* __restrict__ Vg, float* __restrict__ Og) {
  __shared__ AttnSmem sm;
  const int tid = threadIdx.x;
  const int lane = tid & 63;
  const int w = tid >> 6;
  const int h = blockIdx.x & 15;
  const int qb = 31 - (blockIdx.x >> 4);   // heavy blocks first
  const int qrow0 = qb * 128;
  const int l31 = lane & 31;
  const int hi = lane >> 5;

  // ---- stage Q tile (scaled by 1/sqrt(64)), bf16, swizzled ----
  {
    const float* src = Qg + (size_t)qrow0 * D_MODEL + h * HD;
#pragma unroll
    for (int p = 0; p < 8; ++p) {
      int idx = tid + p * 256;
      int row = idx >> 4, c4 = idx & 15;
      float4 v = *(const float4*)(src + (size_t)row * D_MODEL + c4 * 4);
      char* base = (char*)sm.q + row * 128 + ((c4 * 8) ^ ((row & 7) << 4));
      *(uint2*)base = make_uint2(pk2(v.x * 0.125f, v.y * 0.125f),
                                 pk2(v.z * 0.125f, v.w * 0.125f));
    }
  }
  __syncthreads();

  // ---- per-wave Q fragments held in registers (B-operand: col = q = lane&31)
  bf16x8 qf[4];
  {
    int qr = w * 32 + l31;
    char* rb = (char*)sm.q + qr * 128;
    int sw = (qr & 7) << 4;
#pragma unroll
    for (int s = 0; s < 4; ++s)
      qf[s] = *(const bf16x8*)(rb + ((s * 32 + hi * 16) ^ sw));
  }
  __syncthreads();

  f32x16 oacc0, oacc1;   // O^T: d-tiles 0 (d 0..31) and 1 (d 32..63)
#pragma unroll
  for (int r = 0; r < 16; ++r) { oacc0[r] = 0.0f; oacc1[r] = 0.0f; }
  float m_ = -1e30f, l_ = 0.0f;
  const int qg = qrow0 + w * 32 + l31;     // this lane's global q row
  const int qwmax = qrow0 + w * 32 + 31;   // wave's max q row
  const int nT = 2 * qb + 2;

  for (int t = 0; t < nT; ++t) {
    const int k0 = t * 64;
    __syncthreads();
    // ---- stage K (row-major bf16) and V^T (transposed bf16), swizzled ----
    {
      const float* srcK = Kg + (size_t)k0 * D_MODEL + h * HD;
      const float* srcV = Vg + (size_t)k0 * D_MODEL + h * HD;
#pragma unroll
      for (int p = 0; p < 4; ++p) {
        int idx = tid + p * 256;
        int row = idx >> 4, c4 = idx & 15;
        float4 v = *(const float4*)(srcK + (size_t)row * D_MODEL + c4 * 4);
        char* base = (char*)sm.kv.k + row * 128 + ((c4 * 8) ^ ((row & 7) << 4));
        *(uint2*)base = make_uint2(pk2(v.x, v.y), pk2(v.z, v.w));
        float4 u = *(const float4*)(srcV + (size_t)row * D_MODEL + c4 * 4);
        {
          int d = c4 * 4;
          *(unsigned short*)((char*)sm.kv.vt + (d+0) * 128 + ((row * 2) ^ (((d+0) & 7) << 4))) = bf1(u.x);
          *(unsigned short*)((char*)sm.kv.vt + (d+1) * 128 + ((row * 2) ^ (((d+1) & 7) << 4))) = bf1(u.y);
          *(unsigned short*)((char*)sm.kv.vt + (d+2) * 128 + ((row * 2) ^ (((d+2) & 7) << 4))) = bf1(u.z);
          *(unsigned short*)((char*)sm.kv.vt + (d+3) * 128 + ((row * 2) ^ (((d+3) & 7) << 4))) = bf1(u.w);
        }
      }
    }
    __syncthreads();

#pragma unroll
    for (int kh = 0; kh < 2; ++kh) {
      if (k0 + kh * 32 > qwmax) continue;   // wave-level causal skip

      // ---- QK^T: S^T[k][q], accumulate over 4 d-slices of 16 ----
      f32x16 sa;
#pragma unroll
      for (int r = 0; r < 16; ++r) sa[r] = 0.0f;
      {
        int krow = kh * 32 + l31;
        char* kb = (char*)sm.kv.k + krow * 128;
        int sw = (krow & 7) << 4;
#pragma unroll
        for (int s = 0; s < 4; ++s) {
          bf16x8 kf = *(const bf16x8*)(kb + ((s * 32 + hi * 16) ^ sw));
          sa = __builtin_amdgcn_mfma_f32_32x32x16_bf16(kf, qf[s], sa, 0, 0, 0);
        }
      }

      // ---- causal mask (only near the diagonal) ----
      if (k0 + kh * 32 + 31 > qg) {
#pragma unroll
        for (int r = 0; r < 16; ++r) {
          int kg = k0 + kh * 32 + (r & 3) + 8 * (r >> 2) + 4 * hi;
          if (kg > qg) sa[r] = -1e30f;
        }
      }

      // ---- online softmax: lane + its partner (lane^32) share q row ----
      float tm = sa[0];
#pragma unroll
      for (int r = 1; r < 16; ++r) tm = fmaxf(tm, sa[r]);
      tm = fmaxf(tm, __shfl_xor(tm, 32));
      const float mn = fmaxf(m_, tm);
      const float sc = __expf(m_ - mn);
      m_ = mn;
      float rs = 0.0f;
#pragma unroll
      for (int r = 0; r < 16; ++r) {
        float e = __expf(sa[r] - mn);
        sa[r] = e;
        rs += e;
      }
      rs += __shfl_xor(rs, 32);
      l_ = l_ * sc + rs;
#pragma unroll
      for (int r = 0; r < 16; ++r) { oacc0[r] *= sc; oacc1[r] *= sc; }

      // ---- pack P -> bf16 B-fragments (cvt_pk pairs + permlane32_swap) ----
      unsigned a0 = pk2(sa[0],  sa[1]),  b0 = pk2(sa[4],  sa[5]);
      unsigned a1 = pk2(sa[2],  sa[3]),  b1 = pk2(sa[6],  sa[7]);
      unsigned a2 = pk2(sa[8],  sa[9]),  b2 = pk2(sa[12], sa[13]);
      unsigned a3 = pk2(sa[10], sa[11]), b3 = pk2(sa[14], sa[15]);
      asm volatile("v_permlane32_swap_b32 %0, %1" : "+v"(a0), "+v"(b0));
      asm volatile("v_permlane32_swap_b32 %0, %1" : "+v"(a1), "+v"(b1));
      asm volatile("v_permlane32_swap_b32 %0, %1" : "+v"(a2), "+v"(b2));
      asm volatile("v_permlane32_swap_b32 %0, %1" : "+v"(a3), "+v"(b3));
      union FU { unsigned u[4]; bf16x8 v; } f0, f1;
      f0.u[0] = a0; f0.u[1] = a1; f0.u[2] = b0; f0.u[3] = b1;  // k 0..15
      f1.u[0] = a2; f1.u[1] = a3; f1.u[2] = b2; f1.u[3] = b3;  // k 16..31

      // ---- PV: O^T[d][q] += V^T[d][k] * P^T[k][q] ----
      {
        char* vb0 = (char*)sm.kv.vt + l31 * 128;          // d-tile 0 rows
        char* vb1 = (char*)sm.kv.vt + (32 + l31) * 128;   // d-tile 1 rows
        int sw = (l31 & 7) << 4;   // (32+l31)&7 == l31&7
        int off0 = (kh * 64 + hi * 16) ^ sw;
        int off1 = (kh * 64 + 32 + hi * 16) ^ sw;
        bf16x8 v00 = *(const bf16x8*)(vb0 + off0);
        bf16x8 v01 = *(const bf16x8*)(vb0 + off1);
        bf16x8 v10 = *(const bf16x8*)(vb1 + off0);
        bf16x8 v11 = *(const bf16x8*)(vb1 + off1);
        oacc0 = __builtin_amdgcn_mfma_f32_32x32x16_bf16(v00, f0.v, oacc0, 0, 0, 0);
        oacc0 = __builtin_amdgcn_mfma_f32_32x32x16_bf16(v01, f1.v, oacc0, 0, 0, 0);
        oacc1 = __builtin_amdgcn_mfma_f32_32x32x16_bf16(v10, f0.v, oacc1, 0, 0, 0);
        oacc1 = __builtin_amdgcn_mfma_f32_32x32x16_bf16(v11, f1.v, oacc1, 0, 0, 0);
      }
    }  // kh
  }  // t

  // ---- epilogue: normalize, transpose via LDS, coalesced store ----
  __syncthreads();   // all waves done with kv before oep aliases it
  const float inv = 1.0f / l_;
#pragma unroll
  for (int g = 0; g < 4; ++g) {
    *(float4*)&sm.oep[w][l31][8 * g + 4 * hi] =
        make_float4(oacc0[4*g+0] * inv, oacc0[4*g+1] * inv,
                    oacc0[4*g+2] * inv, oacc0[4*g+3] * inv);
    *(float4*)&sm.oep[w][l31][8 * g + 4 * hi + 32] =
        make_float4(oacc1[4*g+0] * inv, oacc1[4*g+1] * inv,
                    oacc1[4*g+2] * inv, oacc1[4*g+3] * inv);
  }
  // same-wave readback: compiler orders via lgkmcnt, no barrier needed
  {
    int qr = lane >> 1, ch = lane & 1;
    const float* rp = &sm.oep[w][qr][ch * 32];
    float* gp = Og + (size_t)(qrow0 + w * 32 + qr) * D_MODEL + h * HD + ch * 32;
#pragma unroll
    for (int j = 0; j < 8; ++j)
      *(float4*)(gp + j * 4) = *(const float4*)(rp + j * 4);
  }
}

// ---------------------------------------------------------------------------
extern "C" void kernel_launch(void* const* d_in, const int* in_sizes, int n_in,
                              void* d_out, int out_size, void* d_ws, size_t ws_size,
                              hipStream_t stream) {
  const float* x   = (const float*)d_in[0];
  const int*   pos = (const int*)d_in[1];
  const float* Wq  = (const float*)d_in[2];
  const float* Wk  = (const float*)d_in[3];
  const float* Wv  = (const float*)d_in[4];
  const float* Wo  = (const float*)d_in[5];
  float* out = (float*)d_out;

  const size_t SD = (size_t)S_LEN * D_MODEL;
  float* Qb = (float*)d_ws;
  float* Kb = Qb + SD;
  float* Vb = Kb + SD;
  float* Ob = Vb + SD;

  dim3 blk(256);
  dim3 gg(D_MODEL / 64, S_LEN / 128);

  hipLaunchKernelGGL((gemm_bt<1>), gg, blk, 0, stream, x, Wq, Qb, pos,
                     S_LEN, D_MODEL, D_MODEL);
  hipLaunchKernelGGL((gemm_bt<1>), gg, blk, 0, stream, x, Wk, Kb, pos,
                     S_LEN, D_MODEL, D_MODEL);
  hipLaunchKernelGGL((gemm_bt<0>), gg, blk, 0, stream, x, Wv, Vb, nullptr,
                     S_LEN, D_MODEL, D_MODEL);

  hipLaunchKernelGGL(attn_mfma, dim3(512), blk, 0, stream, Qb, Kb, Vb, Ob);

  hipLaunchKernelGGL((gemm_bt<0>), gg, blk, 0, stream, Ob, Wo, out, nullptr,
                     S_LEN, D_MODEL, D_MODEL);
}

// Round 4
// 450.194 us; speedup vs baseline: 3.3678x; 1.8554x over previous
//
#include <hip/hip_runtime.h>
#include <hip/hip_bf16.h>
#include <math.h>

// Problem constants (B=1, S=4096, D=1024, H=16, hd=64)
#define S_LEN 4096
#define D_MODEL 1024
#define NHEAD 16
#define HD 64

typedef unsigned short ushort_t;
typedef short bf16x8 __attribute__((ext_vector_type(8)));
typedef float f32x16 __attribute__((ext_vector_type(16)));

static __device__ __forceinline__ unsigned pk2(float lo, float hi) {
  __hip_bfloat162 h = __float22bfloat162_rn(make_float2(lo, hi));
  return *reinterpret_cast<unsigned*>(&h);
}
static __device__ __forceinline__ unsigned short bf1(float x) {
  __hip_bfloat16 h = __float2bfloat16(x);
  return *reinterpret_cast<unsigned short*>(&h);
}
static __device__ __forceinline__ float bff(unsigned short h) {
  unsigned u = ((unsigned)h) << 16;
  return *reinterpret_cast<float*>(&u);
}

// async 16B global->LDS (wave-uniform LDS base + lane*16; per-lane global src)
static __device__ __forceinline__ void gload16(const void* g, void* l) {
  __builtin_amdgcn_global_load_lds(
      (const __attribute__((address_space(1))) unsigned*)g,
      (__attribute__((address_space(3))) unsigned*)l, 16, 0, 0);
}

// ---------------------------------------------------------------------------
// split fp32 -> bf16 hi + bf16 lo (residual). One float4 per thread, stride.
// ---------------------------------------------------------------------------
__global__ __launch_bounds__(256)
void cvt_split(const float* __restrict__ src, unsigned short* __restrict__ hi,
               unsigned short* __restrict__ lo, int n4) {
  for (int i = blockIdx.x * 256 + threadIdx.x; i < n4; i += gridDim.x * 256) {
    float4 v = ((const float4*)src)[i];
    unsigned short h0 = bf1(v.x), h1 = bf1(v.y), h2 = bf1(v.z), h3 = bf1(v.w);
    unsigned short l0 = bf1(v.x - bff(h0)), l1 = bf1(v.y - bff(h1));
    unsigned short l2 = bf1(v.z - bff(h2)), l3 = bf1(v.w - bff(h3));
    ((uint2*)hi)[i] = make_uint2((unsigned)h0 | ((unsigned)h1 << 16),
                                 (unsigned)h2 | ((unsigned)h3 << 16));
    ((uint2*)lo)[i] = make_uint2((unsigned)l0 | ((unsigned)l1 << 16),
                                 (unsigned)l2 | ((unsigned)l3 << 16));
  }
}

// ---------------------------------------------------------------------------
// Split-bf16 MFMA GEMM mainloop. C[m,n] = sum_k A[m,k]*B[n,k], A,B in hi/lo
// bf16 pairs, 3-term product. BM=128, BN=64, BK=32, 256 thr (4 waves 2x2),
// wave tile 64x32 (2 row-blocks of 32x32). Double-buffered LDS, 2-phase.
// LDS layout per buffer (chunk-major, conflict-free b128 reads & linear
// gload_lds dest): A: unit(c,row)=c*128+row (c=k/8), B: unit=c*64+row.
// ---------------------------------------------------------------------------
#define BUFBYTES 24576

static __device__ __forceinline__ void gemm_mainloop(
    const unsigned short* __restrict__ Ah, const unsigned short* __restrict__ Al,
    const unsigned short* __restrict__ Bh, const unsigned short* __restrict__ Bl,
    int tr0, int br0, char* ldsbuf, int tid, f32x16& acc0, f32x16& acc1) {
  const int lane = tid & 63, w = tid >> 6;
  const int l31 = lane & 31, hi5 = lane >> 5;
  const int wr = (w >> 1) * 64, wc = (w & 1) * 32;

  // precompute the 6 staging chunks this wave owns (ch = w + 4j, 0..23)
  const unsigned short* srcs[6];
  int offs[6];
#pragma unroll
  for (int j = 0; j < 6; ++j) {
    int ch = w + 4 * j;
    if (ch < 8) {
      int u = ch * 64 + lane;
      srcs[j] = Ah + (size_t)(tr0 + (u & 127)) * 1024 + (u >> 7) * 8;
      offs[j] = ch * 1024;
    } else if (ch < 16) {
      int c2 = ch - 8, u = c2 * 64 + lane;
      srcs[j] = Al + (size_t)(tr0 + (u & 127)) * 1024 + (u >> 7) * 8;
      offs[j] = 8192 + c2 * 1024;
    } else if (ch < 20) {
      int c2 = ch - 16, u = c2 * 64 + lane;
      srcs[j] = Bh + (size_t)(br0 + (u & 63)) * 1024 + (u >> 6) * 8;
      offs[j] = 16384 + c2 * 1024;
    } else {
      int c2 = ch - 20, u = c2 * 64 + lane;
      srcs[j] = Bl + (size_t)(br0 + (u & 63)) * 1024 + (u >> 6) * 8;
      offs[j] = 20480 + c2 * 1024;
    }
  }

#define STAGE(bufoff, koff)                                           \
  {                                                                   \
    _Pragma("unroll") for (int j = 0; j < 6; ++j)                     \
        gload16(srcs[j] + (koff), ldsbuf + (bufoff) + offs[j]);       \
  }

#define COMPUTE(bufoff)                                               \
  {                                                                   \
    const char* lb = ldsbuf + (bufoff);                               \
    _Pragma("unroll") for (int s = 0; s < 2; ++s) {                   \
      const int c = 2 * s + hi5;                                      \
      const char* pa = lb + (size_t)(c * 128 + wr + l31) * 16;        \
      bf16x8 ah0 = *(const bf16x8*)(pa);                              \
      bf16x8 ah1 = *(const bf16x8*)(pa + 512);                        \
      bf16x8 al0 = *(const bf16x8*)(pa + 8192);                       \
      bf16x8 al1 = *(const bf16x8*)(pa + 8192 + 512);                 \
      const char* pb = lb + 16384 + (size_t)(c * 64 + wc + l31) * 16; \
      bf16x8 bh = *(const bf16x8*)(pb);                               \
      bf16x8 bl = *(const bf16x8*)(pb + 4096);                        \
      acc0 = __builtin_amdgcn_mfma_f32_32x32x16_bf16(ah0, bh, acc0, 0, 0, 0); \
      acc1 = __builtin_amdgcn_mfma_f32_32x32x16_bf16(ah1, bh, acc1, 0, 0, 0); \
      acc0 = __builtin_amdgcn_mfma_f32_32x32x16_bf16(ah0, bl, acc0, 0, 0, 0); \
      acc1 = __builtin_amdgcn_mfma_f32_32x32x16_bf16(ah1, bl, acc1, 0, 0, 0); \
      acc0 = __builtin_amdgcn_mfma_f32_32x32x16_bf16(al0, bh, acc0, 0, 0, 0); \
      acc1 = __builtin_amdgcn_mfma_f32_32x32x16_bf16(al1, bh, acc1, 0, 0, 0); \
    }                                                                 \
  }

  STAGE(0, 0);
  __syncthreads();   // syncthreads drains vmcnt(0) before s_barrier

#pragma unroll 1
  for (int it = 0; it < 16; ++it) {
    const int t0 = 2 * it;
    if (t0 < 31) STAGE(BUFBYTES, (t0 + 1) * 32);
    COMPUTE(0);
    __syncthreads();
    if (t0 + 1 < 31) STAGE(0, (t0 + 2) * 32);
    COMPUTE(BUFBYTES);
    __syncthreads();
  }
#undef STAGE
#undef COMPUTE
}

// ---------------------------------------------------------------------------
// Fused QKV projection GEMM + RoPE epilogue, bf16 outputs.
// grid (48, 32): x = n-block (0..15 Q, 16..31 K, 32..47 V), y = m-block.
// ---------------------------------------------------------------------------
__global__ __launch_bounds__(256)
void qkv_gemm(const unsigned short* __restrict__ xh, const unsigned short* __restrict__ xl,
              const unsigned short* __restrict__ wqh, const unsigned short* __restrict__ wql,
              const unsigned short* __restrict__ wkh, const unsigned short* __restrict__ wkl,
              const unsigned short* __restrict__ wvh, const unsigned short* __restrict__ wvl,
              unsigned short* __restrict__ Qo, unsigned short* __restrict__ Ko,
              unsigned short* __restrict__ Vo, const int* __restrict__ pos) {
  __shared__ __align__(16) char ldsbuf[2 * BUFBYTES];
  const int tid = threadIdx.x;
  const int nb = blockIdx.x;
  const int which = nb >> 4;          // 0=Q 1=K 2=V
  const int br0 = (nb & 15) * 64;     // col block within the 1024-wide W
  const int tr0 = blockIdx.y * 128;

  const unsigned short* Bh = (which == 0) ? wqh : (which == 1) ? wkh : wvh;
  const unsigned short* Bl = (which == 0) ? wql : (which == 1) ? wkl : wvl;
  unsigned short* Out = (which == 0) ? Qo : (which == 1) ? Ko : Vo;

  f32x16 acc0, acc1;
#pragma unroll
  for (int r = 0; r < 16; ++r) { acc0[r] = 0.0f; acc1[r] = 0.0f; }

  gemm_mainloop(xh, xl, Bh, Bl, tr0, br0, ldsbuf, tid, acc0, acc1);

  // epilogue: RoPE (Q,K) + scale (Q) + bf16 pack/store
  const int lane = tid & 63, w = tid >> 6;
  const int l31 = lane & 31, hi5 = lane >> 5;
  const int wr = (w >> 1) * 64, wc = (w & 1) * 32;
  const int n = br0 + wc + l31;        // 0..1023
  const int ch = n & 63;               // channel within head
  const float fr = 1.0f / powf(10000.0f, (float)(ch & ~1) * (1.0f / 64.0f));
  const float qs = (which == 0) ? 0.125f : 1.0f;

#pragma unroll
  for (int rb = 0; rb < 2; ++rb) {
    const f32x16& a = rb ? acc1 : acc0;
#pragma unroll
    for (int r = 0; r < 16; ++r) {
      const int m = tr0 + wr + rb * 32 + (r & 3) + 8 * (r >> 2) + 4 * hi5;
      float v = a[r];
      if (which < 2) {
        const float ang = (float)pos[m] * fr;
        float sn, cs;
        __sincosf(ang, &sn, &cs);
        const float vp = __shfl_xor(v, 1);
        v = (ch & 1) ? (vp * sn + v * cs) : (v * cs - vp * sn);
        v *= qs;
      }
      const float nv = __shfl_xor(v, 1);
      if ((ch & 1) == 0) {   // even lane writes the (even,odd) bf16 pair
        *(unsigned*)(Out + (size_t)m * 1024 + n) = pk2(v, nv);
      }
    }
  }
}

// ---------------------------------------------------------------------------
// Output projection GEMM: out = O @ Wo^T, fp32 store. grid (16, 32).
// ---------------------------------------------------------------------------
__global__ __launch_bounds__(256)
void out_gemm(const unsigned short* __restrict__ ah, const unsigned short* __restrict__ al,
              const unsigned short* __restrict__ bh, const unsigned short* __restrict__ bl,
              float* __restrict__ out) {
  __shared__ __align__(16) char ldsbuf[2 * BUFBYTES];
  const int tid = threadIdx.x;
  const int br0 = blockIdx.x * 64;
  const int tr0 = blockIdx.y * 128;

  f32x16 acc0, acc1;
#pragma unroll
  for (int r = 0; r < 16; ++r) { acc0[r] = 0.0f; acc1[r] = 0.0f; }

  gemm_mainloop(ah, al, bh, bl, tr0, br0, ldsbuf, tid, acc0, acc1);

  const int lane = tid & 63, w = tid >> 6;
  const int l31 = lane & 31, hi5 = lane >> 5;
  const int wr = (w >> 1) * 64, wc = (w & 1) * 32;
  const int n = br0 + wc + l31;
#pragma unroll
  for (int rb = 0; rb < 2; ++rb) {
    const f32x16& a = rb ? acc1 : acc0;
#pragma unroll
    for (int r = 0; r < 16; ++r) {
      const int m = tr0 + wr + rb * 32 + (r & 3) + 8 * (r >> 2) + 4 * hi5;
      out[(size_t)m * 1024 + n] = a[r];
    }
  }
}

// ---------------------------------------------------------------------------
// bf16 MFMA flash attention (round-3 proven core; I/O now bf16).
// Q comes pre-scaled by 1/8 from qkv_gemm. Output written as split bf16
// (hi + lo residual) for the out_gemm.
// ---------------------------------------------------------------------------
union __align__(16) AttnSmem {
  unsigned short q[128 * 64];                                  // 16 KB
  struct { unsigned short k[64 * 64]; unsigned short vt[64 * 64]; } kv;  // 16 KB
  float oep[4][32][68];                                        // 34 KB
};

__global__ __launch_bounds__(256)
void attn_mfma(const unsigned short* __restrict__ Qg, const unsigned short* __restrict__ Kg,
               const unsigned short* __restrict__ Vg, unsigned short* __restrict__ obh,
               unsigned short* __restrict__ obl) {
  __shared__ AttnSmem sm;
  const int tid = threadIdx.x;
  const int lane = tid & 63;
  const int w = tid >> 6;
  const int h = blockIdx.x & 15;
  const int qb = 31 - (blockIdx.x >> 4);   // heavy blocks first
  const int qrow0 = qb * 128;
  const int l31 = lane & 31;
  const int hi = lane >> 5;

  // ---- stage Q tile (bf16, already scaled), swizzled ----
  {
    const unsigned short* src = Qg + (size_t)qrow0 * D_MODEL + h * HD;
#pragma unroll
    for (int p = 0; p < 4; ++p) {
      int idx = tid + p * 256;
      int row = idx >> 3, c8 = idx & 7;
      bf16x8 v = *(const bf16x8*)(src + (size_t)row * D_MODEL + c8 * 8);
      *(bf16x8*)((char*)sm.q + row * 128 + ((c8 * 16) ^ ((row & 7) << 4))) = v;
    }
  }
  __syncthreads();

  // ---- per-wave Q fragments held in registers (B-operand: col = q = lane&31)
  bf16x8 qf[4];
  {
    int qr = w * 32 + l31;
    char* rb = (char*)sm.q + qr * 128;
    int sw = (qr & 7) << 4;
#pragma unroll
    for (int s = 0; s < 4; ++s)
      qf[s] = *(const bf16x8*)(rb + ((s * 32 + hi * 16) ^ sw));
  }
  __syncthreads();

  f32x16 oacc0, oacc1;   // O^T: d-tiles 0 (d 0..31) and 1 (d 32..63)
#pragma unroll
  for (int r = 0; r < 16; ++r) { oacc0[r] = 0.0f; oacc1[r] = 0.0f; }
  float m_ = -1e30f, l_ = 0.0f;
  const int qg = qrow0 + w * 32 + l31;     // this lane's global q row
  const int qwmax = qrow0 + w * 32 + 31;   // wave's max q row
  const int nT = 2 * qb + 2;

  for (int t = 0; t < nT; ++t) {
    const int k0 = t * 64;
    __syncthreads();
    // ---- stage K (row-major bf16) and V^T (transposed bf16), swizzled ----
    {
      const unsigned short* srcK = Kg + (size_t)k0 * D_MODEL + h * HD;
      const unsigned short* srcV = Vg + (size_t)k0 * D_MODEL + h * HD;
#pragma unroll
      for (int p = 0; p < 2; ++p) {
        int idx = tid + p * 256;
        int row = idx >> 3, c8 = idx & 7;
        bf16x8 v = *(const bf16x8*)(srcK + (size_t)row * D_MODEL + c8 * 8);
        *(bf16x8*)((char*)sm.kv.k + row * 128 + ((c8 * 16) ^ ((row & 7) << 4))) = v;
      }
#pragma unroll
      for (int p = 0; p < 4; ++p) {
        int idx = tid + p * 256;
        int row = idx >> 4, c4 = idx & 15;
        uint2 u = *(const uint2*)(srcV + (size_t)row * D_MODEL + c4 * 4);
        int d = c4 * 4;
        unsigned short e0 = (unsigned short)(u.x), e1 = (unsigned short)(u.x >> 16);
        unsigned short e2 = (unsigned short)(u.y), e3 = (unsigned short)(u.y >> 16);
        *(unsigned short*)((char*)sm.kv.vt + (d+0) * 128 + ((row * 2) ^ (((d+0) & 7) << 4))) = e0;
        *(unsigned short*)((char*)sm.kv.vt + (d+1) * 128 + ((row * 2) ^ (((d+1) & 7) << 4))) = e1;
        *(unsigned short*)((char*)sm.kv.vt + (d+2) * 128 + ((row * 2) ^ (((d+2) & 7) << 4))) = e2;
        *(unsigned short*)((char*)sm.kv.vt + (d+3) * 128 + ((row * 2) ^ (((d+3) & 7) << 4))) = e3;
      }
    }
    __syncthreads();

#pragma unroll
    for (int kh = 0; kh < 2; ++kh) {
      if (k0 + kh * 32 > qwmax) continue;   // wave-level causal skip

      // ---- QK^T: S^T[k][q], accumulate over 4 d-slices of 16 ----
      f32x16 sa;
#pragma unroll
      for (int r = 0; r < 16; ++r) sa[r] = 0.0f;
      {
        int krow = kh * 32 + l31;
        char* kb = (char*)sm.kv.k + krow * 128;
        int sw = (krow & 7) << 4;
#pragma unroll
        for (int s = 0; s < 4; ++s) {
          bf16x8 kf = *(const bf16x8*)(kb + ((s * 32 + hi * 16) ^ sw));
          sa = __builtin_amdgcn_mfma_f32_32x32x16_bf16(kf, qf[s], sa, 0, 0, 0);
        }
      }

      // ---- causal mask (only near the diagonal) ----
      if (k0 + kh * 32 + 31 > qg) {
#pragma unroll
        for (int r = 0; r < 16; ++r) {
          int kg = k0 + kh * 32 + (r & 3) + 8 * (r >> 2) + 4 * hi;
          if (kg > qg) sa[r] = -1e30f;
        }
      }

      // ---- online softmax: lane + its partner (lane^32) share q row ----
      float tm = sa[0];
#pragma unroll
      for (int r = 1; r < 16; ++r) tm = fmaxf(tm, sa[r]);
      tm = fmaxf(tm, __shfl_xor(tm, 32));
      const float mn = fmaxf(m_, tm);
      const float sc = __expf(m_ - mn);
      m_ = mn;
      float rs = 0.0f;
#pragma unroll
      for (int r = 0; r < 16; ++r) {
        float e = __expf(sa[r] - mn);
        sa[r] = e;
        rs += e;
      }
      rs += __shfl_xor(rs, 32);
      l_ = l_ * sc + rs;
#pragma unroll
      for (int r = 0; r < 16; ++r) { oacc0[r] *= sc; oacc1[r] *= sc; }

      // ---- pack P -> bf16 B-fragments (cvt_pk pairs + permlane32_swap) ----
      unsigned a0 = pk2(sa[0],  sa[1]),  b0 = pk2(sa[4],  sa[5]);
      unsigned a1 = pk2(sa[2],  sa[3]),  b1 = pk2(sa[6],  sa[7]);
      unsigned a2 = pk2(sa[8],  sa[9]),  b2 = pk2(sa[12], sa[13]);
      unsigned a3 = pk2(sa[10], sa[11]), b3 = pk2(sa[14], sa[15]);
      asm volatile("v_permlane32_swap_b32 %0, %1" : "+v"(a0), "+v"(b0));
      asm volatile("v_permlane32_swap_b32 %0, %1" : "+v"(a1), "+v"(b1));
      asm volatile("v_permlane32_swap_b32 %0, %1" : "+v"(a2), "+v"(b2));
      asm volatile("v_permlane32_swap_b32 %0, %1" : "+v"(a3), "+v"(b3));
      union FU { unsigned u[4]; bf16x8 v; } f0, f1;
      f0.u[0] = a0; f0.u[1] = a1; f0.u[2] = b0; f0.u[3] = b1;  // k 0..15
      f1.u[0] = a2; f1.u[1] = a3; f1.u[2] = b2; f1.u[3] = b3;  // k 16..31

      // ---- PV: O^T[d][q] += V^T[d][k] * P^T[k][q] ----
      {
        char* vb0 = (char*)sm.kv.vt + l31 * 128;          // d-tile 0 rows
        char* vb1 = (char*)sm.kv.vt + (32 + l31) * 128;   // d-tile 1 rows
        int sw = (l31 & 7) << 4;   // (32+l31)&7 == l31&7
        int off0 = (kh * 64 + hi * 16) ^ sw;
        int off1 = (kh * 64 + 32 + hi * 16) ^ sw;
        bf16x8 v00 = *(const bf16x8*)(vb0 + off0);
        bf16x8 v01 = *(const bf16x8*)(vb0 + off1);
        bf16x8 v10 = *(const bf16x8*)(vb1 + off0);
        bf16x8 v11 = *(const bf16x8*)(vb1 + off1);
        oacc0 = __builtin_amdgcn_mfma_f32_32x32x16_bf16(v00, f0.v, oacc0, 0, 0, 0);
        oacc0 = __builtin_amdgcn_mfma_f32_32x32x16_bf16(v01, f1.v, oacc0, 0, 0, 0);
        oacc1 = __builtin_amdgcn_mfma_f32_32x32x16_bf16(v10, f0.v, oacc1, 0, 0, 0);
        oacc1 = __builtin_amdgcn_mfma_f32_32x32x16_bf16(v11, f1.v, oacc1, 0, 0, 0);
      }
    }  // kh
  }  // t

  // ---- epilogue: normalize, transpose via LDS, split-bf16 store ----
  __syncthreads();   // all waves done with kv before oep aliases it
  const float inv = 1.0f / l_;
#pragma unroll
  for (int g = 0; g < 4; ++g) {
    *(float4*)&sm.oep[w][l31][8 * g + 4 * hi] =
        make_float4(oacc0[4*g+0] * inv, oacc0[4*g+1] * inv,
                    oacc0[4*g+2] * inv, oacc0[4*g+3] * inv);
    *(float4*)&sm.oep[w][l31][8 * g + 4 * hi + 32] =
        make_float4(oacc1[4*g+0] * inv, oacc1[4*g+1] * inv,
                    oacc1[4*g+2] * inv, oacc1[4*g+3] * inv);
  }
  // same-wave readback: compiler orders via lgkmcnt, no barrier needed
  {
    int qr = lane >> 1, chh = lane & 1;
    const float* rp = &sm.oep[w][qr][chh * 32];
    const size_t base = (size_t)(qrow0 + w * 32 + qr) * D_MODEL + h * HD + chh * 32;
#pragma unroll
    for (int j = 0; j < 8; ++j) {
      float4 v = *(const float4*)(rp + j * 4);
      unsigned short h0 = bf1(v.x), h1 = bf1(v.y), h2 = bf1(v.z), h3 = bf1(v.w);
      unsigned short l0 = bf1(v.x - bff(h0)), l1 = bf1(v.y - bff(h1));
      unsigned short l2 = bf1(v.z - bff(h2)), l3 = bf1(v.w - bff(h3));
      *(uint2*)(obh + base + j * 4) = make_uint2((unsigned)h0 | ((unsigned)h1 << 16),
                                                 (unsigned)h2 | ((unsigned)h3 << 16));
      *(uint2*)(obl + base + j * 4) = make_uint2((unsigned)l0 | ((unsigned)l1 << 16),
                                                 (unsigned)l2 | ((unsigned)l3 << 16));
    }
  }
}

// ---------------------------------------------------------------------------
// Workspace layout (bytes):
//  [0,8M)    xh        -> later obh (attn output hi)
//  [8M,16M)  xl        -> later obl
//  [16M,18M) wqh  [18M,20M) wql   -> later woh / wol
//  [20M,22M) wkh  [22M,24M) wkl
//  [24M,26M) wvh  [26M,28M) wvl
//  [28M,36M) Qb (bf16)  [36M,44M) Kb  [44M,52M) Vb
// ---------------------------------------------------------------------------
extern "C" void kernel_launch(void* const* d_in, const int* in_sizes, int n_in,
                              void* d_out, int out_size, void* d_ws, size_t ws_size,
                              hipStream_t stream) {
  const float* x   = (const float*)d_in[0];
  const int*   pos = (const int*)d_in[1];
  const float* Wq  = (const float*)d_in[2];
  const float* Wk  = (const float*)d_in[3];
  const float* Wv  = (const float*)d_in[4];
  const float* Wo  = (const float*)d_in[5];
  float* out = (float*)d_out;

  char* ws = (char*)d_ws;
  const size_t MB = 1024 * 1024;
  unsigned short* xh  = (unsigned short*)(ws);
  unsigned short* xl  = (unsigned short*)(ws + 8 * MB);
  unsigned short* wqh = (unsigned short*)(ws + 16 * MB);
  unsigned short* wql = (unsigned short*)(ws + 18 * MB);
  unsigned short* wkh = (unsigned short*)(ws + 20 * MB);
  unsigned short* wkl = (unsigned short*)(ws + 22 * MB);
  unsigned short* wvh = (unsigned short*)(ws + 24 * MB);
  unsigned short* wvl = (unsigned short*)(ws + 26 * MB);
  unsigned short* Qb  = (unsigned short*)(ws + 28 * MB);
  unsigned short* Kb  = (unsigned short*)(ws + 36 * MB);
  unsigned short* Vb  = (unsigned short*)(ws + 44 * MB);
  unsigned short* obh = xh;   // x dead after qkv_gemm
  unsigned short* obl = xl;
  unsigned short* woh = wqh;  // W-qkv splits dead after qkv_gemm
  unsigned short* wol = wql;

  dim3 blk(256);

  // split conversions
  hipLaunchKernelGGL(cvt_split, dim3(2048), blk, 0, stream, x, xh, xl,
                     (int)((size_t)S_LEN * D_MODEL / 4));
  const int w4 = D_MODEL * D_MODEL / 4;
  hipLaunchKernelGGL(cvt_split, dim3(1024), blk, 0, stream, Wq, wqh, wql, w4);
  hipLaunchKernelGGL(cvt_split, dim3(1024), blk, 0, stream, Wk, wkh, wkl, w4);
  hipLaunchKernelGGL(cvt_split, dim3(1024), blk, 0, stream, Wv, wvh, wvl, w4);

  // fused QKV projection + RoPE (Q scaled by 1/8), bf16 outputs
  hipLaunchKernelGGL(qkv_gemm, dim3(48, 32), blk, 0, stream,
                     xh, xl, wqh, wql, wkh, wkl, wvh, wvl, Qb, Kb, Vb, pos);

  // Wo split (region freed by qkv_gemm completion; stream-ordered)
  hipLaunchKernelGGL(cvt_split, dim3(1024), blk, 0, stream, Wo, woh, wol, w4);

  // flash attention (writes split-bf16 O into xh/xl region)
  hipLaunchKernelGGL(attn_mfma, dim3(512), blk, 0, stream, Qb, Kb, Vb, obh, obl);

  // output projection, fp32 to d_out
  hipLaunchKernelGGL(out_gemm, dim3(16, 32), blk, 0, stream,
                     obh, obl, woh, wol, out);
}

// Round 6
// 349.154 us; speedup vs baseline: 4.3424x; 1.2894x over previous
//
#include <hip/hip_runtime.h>
#include <hip/hip_bf16.h>
#include <math.h>

// Problem constants (B=1, S=4096, D=1024, H=16, hd=64)
#define S_LEN 4096
#define D_MODEL 1024
#define NHEAD 16
#define HD 64

typedef short bf16x8 __attribute__((ext_vector_type(8)));
typedef float f32x16 __attribute__((ext_vector_type(16)));
typedef _Float16 f16x8 __attribute__((ext_vector_type(8)));
typedef _Float16 f16x4 __attribute__((ext_vector_type(4)));

static __device__ __forceinline__ unsigned pk2(float lo, float hi) {
  __hip_bfloat162 h = __float22bfloat162_rn(make_float2(lo, hi));
  return *reinterpret_cast<unsigned*>(&h);
}

// async 16B global->LDS (wave-uniform LDS base + lane*16; per-lane global src)
static __device__ __forceinline__ void gload16(const void* g, void* l) {
  __builtin_amdgcn_global_load_lds(
      (const __attribute__((address_space(1))) unsigned*)g,
      (__attribute__((address_space(3))) unsigned*)l, 16, 0, 0);
}

// ---------------------------------------------------------------------------
// fp32 -> fp16 converts
// ---------------------------------------------------------------------------
__global__ __launch_bounds__(256)
void cvt_f16(const float* __restrict__ src, _Float16* __restrict__ dst, int n4) {
  for (int i = blockIdx.x * 256 + threadIdx.x; i < n4; i += gridDim.x * 256) {
    float4 v = ((const float4*)src)[i];
    f16x4 o;
    o[0] = (_Float16)v.x; o[1] = (_Float16)v.y;
    o[2] = (_Float16)v.z; o[3] = (_Float16)v.w;
    ((f16x4*)dst)[i] = o;
  }
}

__global__ __launch_bounds__(256)
void cvt4_f16(const float* __restrict__ s0, const float* __restrict__ s1,
              const float* __restrict__ s2, const float* __restrict__ s3,
              _Float16* __restrict__ d0, _Float16* __restrict__ d1,
              _Float16* __restrict__ d2, _Float16* __restrict__ d3, int n4) {
  const float* s = (blockIdx.y == 0) ? s0 : (blockIdx.y == 1) ? s1
                 : (blockIdx.y == 2) ? s2 : s3;
  _Float16* d = (blockIdx.y == 0) ? d0 : (blockIdx.y == 1) ? d1
              : (blockIdx.y == 2) ? d2 : d3;
  for (int i = blockIdx.x * 256 + threadIdx.x; i < n4; i += gridDim.x * 256) {
    float4 v = ((const float4*)s)[i];
    f16x4 o;
    o[0] = (_Float16)v.x; o[1] = (_Float16)v.y;
    o[2] = (_Float16)v.z; o[3] = (_Float16)v.w;
    ((f16x4*)d)[i] = o;
  }
}

// ---------------------------------------------------------------------------
// fp16 MFMA GEMM mainloop. C[m,n] = sum_k A[m,k]*B[n,k] (B row-major N x K).
// BM=128, BN=128, BK=32, 256 thr (4 waves 2x2), wave tile 64x64 (4 accs).
// Double-buffered LDS, proven 2-phase sync. Chunk-major LDS (conflict-free
// ds_read_b128 + linear gload_lds dest): unit(c,row) = c*128+row, c = k/8.
// A region [0,8192), B region [8192,16384) per buffer.
// ---------------------------------------------------------------------------
#define BUFBYTES 16384

static __device__ __forceinline__ void gemm_mainloop_f16(
    const _Float16* __restrict__ A, const _Float16* __restrict__ B,
    int tr0, int br0, char* ldsbuf, int tid,
    f32x16& acc00, f32x16& acc01, f32x16& acc10, f32x16& acc11) {
  const int lane = tid & 63, w = tid >> 6;
  const int l31 = lane & 31, hi5 = lane >> 5;
  const int wr = (w >> 1) * 64, wc = (w & 1) * 64;

  // staging: 16 units of 1024B; wave w owns ch = w + 4j (j=0..3)
  const _Float16* srcs[4];
  int offs[4];
#pragma unroll
  for (int j = 0; j < 4; ++j) {
    int ch = w + 4 * j;
    if (ch < 8) {            // A units
      int u = ch * 64 + lane;          // = c*128 + row
      srcs[j] = A + (size_t)(tr0 + (u & 127)) * 1024 + (u >> 7) * 8;
      offs[j] = ch * 1024;
    } else {                 // B units
      int u = (ch - 8) * 64 + lane;
      srcs[j] = B + (size_t)(br0 + (u & 127)) * 1024 + (u >> 7) * 8;
      offs[j] = 8192 + (ch - 8) * 1024;
    }
  }

#define STAGE(bufoff, koff)                                           \
  {                                                                   \
    _Pragma("unroll") for (int j = 0; j < 4; ++j)                     \
        gload16(srcs[j] + (koff), ldsbuf + (bufoff) + offs[j]);       \
  }

#define COMPUTE(bufoff)                                               \
  {                                                                   \
    const char* lb = ldsbuf + (bufoff);                               \
    _Pragma("unroll") for (int s = 0; s < 2; ++s) {                   \
      const int c = 2 * s + hi5;                                      \
      const char* pa = lb + (size_t)(c * 128 + wr + l31) * 16;        \
      f16x8 a0 = *(const f16x8*)(pa);                                 \
      f16x8 a1 = *(const f16x8*)(pa + 512);                           \
      const char* pb = lb + 8192 + (size_t)(c * 128 + wc + l31) * 16; \
      f16x8 b0 = *(const f16x8*)(pb);                                 \
      f16x8 b1 = *(const f16x8*)(pb + 512);                           \
      acc00 = __builtin_amdgcn_mfma_f32_32x32x16_f16(a0, b0, acc00, 0, 0, 0); \
      acc01 = __builtin_amdgcn_mfma_f32_32x32x16_f16(a0, b1, acc01, 0, 0, 0); \
      acc10 = __builtin_amdgcn_mfma_f32_32x32x16_f16(a1, b0, acc10, 0, 0, 0); \
      acc11 = __builtin_amdgcn_mfma_f32_32x32x16_f16(a1, b1, acc11, 0, 0, 0); \
    }                                                                 \
  }

  STAGE(0, 0);
  __syncthreads();   // syncthreads drains vmcnt(0) before s_barrier

#pragma unroll 1
  for (int it = 0; it < 16; ++it) {
    const int t0 = 2 * it;
    if (t0 < 31) STAGE(BUFBYTES, (t0 + 1) * 32);
    COMPUTE(0);
    __syncthreads();
    if (t0 + 1 < 31) STAGE(0, (t0 + 2) * 32);
    COMPUTE(BUFBYTES);
    __syncthreads();
  }
#undef STAGE
#undef COMPUTE
}

// ---------------------------------------------------------------------------
// Fused QKV projection GEMM + RoPE epilogue, bf16 outputs (Q pre-scaled 1/8).
// grid (24, 32): x = n-block (0..7 Q, 8..15 K, 16..23 V), y = m-block.
// ---------------------------------------------------------------------------
__global__ __launch_bounds__(256)
void qkv_gemm(const _Float16* __restrict__ xf,
              const _Float16* __restrict__ wqf, const _Float16* __restrict__ wkf,
              const _Float16* __restrict__ wvf,
              unsigned short* __restrict__ Qo, unsigned short* __restrict__ Ko,
              unsigned short* __restrict__ Vo, const int* __restrict__ pos) {
  __shared__ __align__(16) char ldsbuf[2 * BUFBYTES];
  const int tid = threadIdx.x;
  const int nb = blockIdx.x;
  const int which = nb >> 3;          // 0=Q 1=K 2=V
  const int br0 = (nb & 7) * 128;
  const int tr0 = blockIdx.y * 128;

  const _Float16* Bsrc = (which == 0) ? wqf : (which == 1) ? wkf : wvf;
  unsigned short* Out = (which == 0) ? Qo : (which == 1) ? Ko : Vo;

  f32x16 acc00, acc01, acc10, acc11;
#pragma unroll
  for (int r = 0; r < 16; ++r) {
    acc00[r] = 0.0f; acc01[r] = 0.0f; acc10[r] = 0.0f; acc11[r] = 0.0f;
  }

  gemm_mainloop_f16(xf, Bsrc, tr0, br0, ldsbuf, tid, acc00, acc01, acc10, acc11);

  // epilogue: RoPE (Q,K) + scale (Q) + bf16 pack/store
  const int lane = tid & 63, w = tid >> 6;
  const int l31 = lane & 31, hi5 = lane >> 5;
  const int wr = (w >> 1) * 64, wc = (w & 1) * 64;
  const float qs = (which == 0) ? 0.125f : 1.0f;

#pragma unroll
  for (int bc = 0; bc < 2; ++bc) {
    const int n = br0 + wc + bc * 32 + l31;   // output column 0..1023
    const int ch = n & 63;                    // channel within head
    const float fr = 1.0f / powf(10000.0f, (float)(ch & ~1) * (1.0f / 64.0f));
#pragma unroll
    for (int ar = 0; ar < 2; ++ar) {
      const f32x16& a = ar ? (bc ? acc11 : acc10) : (bc ? acc01 : acc00);
#pragma unroll
      for (int r = 0; r < 16; ++r) {
        const int m = tr0 + wr + ar * 32 + (r & 3) + 8 * (r >> 2) + 4 * hi5;
        float v = a[r];
        if (which < 2) {
          const float ang = (float)pos[m] * fr;
          float sn, cs;
          __sincosf(ang, &sn, &cs);
          const float vp = __shfl_xor(v, 1);
          v = (ch & 1) ? (vp * sn + v * cs) : (v * cs - vp * sn);
          v *= qs;
        }
        const float nv = __shfl_xor(v, 1);
        if ((ch & 1) == 0) {   // even lane writes the (even,odd) bf16 pair
          *(unsigned*)(Out + (size_t)m * 1024 + n) = pk2(v, nv);
        }
      }
    }
  }
}

// ---------------------------------------------------------------------------
// Output projection GEMM: out = O @ Wo^T, fp32 store. grid (8, 32).
// ---------------------------------------------------------------------------
__global__ __launch_bounds__(256)
void out_gemm(const _Float16* __restrict__ Of, const _Float16* __restrict__ Wof,
              float* __restrict__ out) {
  __shared__ __align__(16) char ldsbuf[2 * BUFBYTES];
  const int tid = threadIdx.x;
  const int br0 = blockIdx.x * 128;
  const int tr0 = blockIdx.y * 128;

  f32x16 acc00, acc01, acc10, acc11;
#pragma unroll
  for (int r = 0; r < 16; ++r) {
    acc00[r] = 0.0f; acc01[r] = 0.0f; acc10[r] = 0.0f; acc11[r] = 0.0f;
  }

  gemm_mainloop_f16(Of, Wof, tr0, br0, ldsbuf, tid, acc00, acc01, acc10, acc11);

  const int lane = tid & 63, w = tid >> 6;
  const int l31 = lane & 31, hi5 = lane >> 5;
  const int wr = (w >> 1) * 64, wc = (w & 1) * 64;
#pragma unroll
  for (int bc = 0; bc < 2; ++bc) {
    const int n = br0 + wc + bc * 32 + l31;
#pragma unroll
    for (int ar = 0; ar < 2; ++ar) {
      const f32x16& a = ar ? (bc ? acc11 : acc10) : (bc ? acc01 : acc00);
#pragma unroll
      for (int r = 0; r < 16; ++r) {
        const int m = tr0 + wr + ar * 32 + (r & 3) + 8 * (r >> 2) + 4 * hi5;
        out[(size_t)m * 1024 + n] = a[r];
      }
    }
  }
}

// ---------------------------------------------------------------------------
// bf16 MFMA flash attention (round-3/4 proven core; output now fp16).
// Q comes pre-scaled by 1/8 from qkv_gemm.
// ---------------------------------------------------------------------------
union __align__(16) AttnSmem {
  unsigned short q[128 * 64];                                  // 16 KB
  struct { unsigned short k[64 * 64]; unsigned short vt[64 * 64]; } kv;  // 16 KB
  float oep[4][32][68];                                        // 34 KB
};

__global__ __launch_bounds__(256)
void attn_mfma(const unsigned short* __restrict__ Qg, const unsigned short* __restrict__ Kg,
               const unsigned short* __restrict__ Vg, _Float16* __restrict__ Of) {
  __shared__ AttnSmem sm;
  const int tid = threadIdx.x;
  const int lane = tid & 63;
  const int w = tid >> 6;
  const int h = blockIdx.x & 15;
  const int qb = 31 - (blockIdx.x >> 4);   // heavy blocks first
  const int qrow0 = qb * 128;
  const int l31 = lane & 31;
  const int hi = lane >> 5;

  // ---- stage Q tile (bf16, already scaled), swizzled ----
  {
    const unsigned short* src = Qg + (size_t)qrow0 * D_MODEL + h * HD;
#pragma unroll
    for (int p = 0; p < 4; ++p) {
      int idx = tid + p * 256;
      int row = idx >> 3, c8 = idx & 7;
      bf16x8 v = *(const bf16x8*)(src + (size_t)row * D_MODEL + c8 * 8);
      *(bf16x8*)((char*)sm.q + row * 128 + ((c8 * 16) ^ ((row & 7) << 4))) = v;
    }
  }
  __syncthreads();

  // ---- per-wave Q fragments held in registers (B-operand: col = q = lane&31)
  bf16x8 qf[4];
  {
    int qr = w * 32 + l31;
    char* rb = (char*)sm.q + qr * 128;
    int sw = (qr & 7) << 4;
#pragma unroll
    for (int s = 0; s < 4; ++s)
      qf[s] = *(const bf16x8*)(rb + ((s * 32 + hi * 16) ^ sw));
  }
  __syncthreads();

  f32x16 oacc0, oacc1;   // O^T: d-tiles 0 (d 0..31) and 1 (d 32..63)
#pragma unroll
  for (int r = 0; r < 16; ++r) { oacc0[r] = 0.0f; oacc1[r] = 0.0f; }
  float m_ = -1e30f, l_ = 0.0f;
  const int qg = qrow0 + w * 32 + l31;     // this lane's global q row
  const int qwmax = qrow0 + w * 32 + 31;   // wave's max q row
  const int nT = 2 * qb + 2;

  for (int t = 0; t < nT; ++t) {
    const int k0 = t * 64;
    __syncthreads();
    // ---- stage K (row-major bf16) and V^T (transposed bf16), swizzled ----
    {
      const unsigned short* srcK = Kg + (size_t)k0 * D_MODEL + h * HD;
      const unsigned short* srcV = Vg + (size_t)k0 * D_MODEL + h * HD;
#pragma unroll
      for (int p = 0; p < 2; ++p) {
        int idx = tid + p * 256;
        int row = idx >> 3, c8 = idx & 7;
        bf16x8 v = *(const bf16x8*)(srcK + (size_t)row * D_MODEL + c8 * 8);
        *(bf16x8*)((char*)sm.kv.k + row * 128 + ((c8 * 16) ^ ((row & 7) << 4))) = v;
      }
#pragma unroll
      for (int p = 0; p < 4; ++p) {
        int idx = tid + p * 256;
        int row = idx >> 4, c4 = idx & 15;
        uint2 u = *(const uint2*)(srcV + (size_t)row * D_MODEL + c4 * 4);
        int d = c4 * 4;
        unsigned short e0 = (unsigned short)(u.x), e1 = (unsigned short)(u.x >> 16);
        unsigned short e2 = (unsigned short)(u.y), e3 = (unsigned short)(u.y >> 16);
        *(unsigned short*)((char*)sm.kv.vt + (d+0) * 128 + ((row * 2) ^ (((d+0) & 7) << 4))) = e0;
        *(unsigned short*)((char*)sm.kv.vt + (d+1) * 128 + ((row * 2) ^ (((d+1) & 7) << 4))) = e1;
        *(unsigned short*)((char*)sm.kv.vt + (d+2) * 128 + ((row * 2) ^ (((d+2) & 7) << 4))) = e2;
        *(unsigned short*)((char*)sm.kv.vt + (d+3) * 128 + ((row * 2) ^ (((d+3) & 7) << 4))) = e3;
      }
    }
    __syncthreads();

#pragma unroll
    for (int kh = 0; kh < 2; ++kh) {
      if (k0 + kh * 32 > qwmax) continue;   // wave-level causal skip

      // ---- QK^T: S^T[k][q], accumulate over 4 d-slices of 16 ----
      f32x16 sa;
#pragma unroll
      for (int r = 0; r < 16; ++r) sa[r] = 0.0f;
      {
        int krow = kh * 32 + l31;
        char* kb = (char*)sm.kv.k + krow * 128;
        int sw = (krow & 7) << 4;
#pragma unroll
        for (int s = 0; s < 4; ++s) {
          bf16x8 kf = *(const bf16x8*)(kb + ((s * 32 + hi * 16) ^ sw));
          sa = __builtin_amdgcn_mfma_f32_32x32x16_bf16(kf, qf[s], sa, 0, 0, 0);
        }
      }

      // ---- causal mask (only near the diagonal) ----
      if (k0 + kh * 32 + 31 > qg) {
#pragma unroll
        for (int r = 0; r < 16; ++r) {
          int kg = k0 + kh * 32 + (r & 3) + 8 * (r >> 2) + 4 * hi;
          if (kg > qg) sa[r] = -1e30f;
        }
      }

      // ---- online softmax: lane + its partner (lane^32) share q row ----
      float tm = sa[0];
#pragma unroll
      for (int r = 1; r < 16; ++r) tm = fmaxf(tm, sa[r]);
      tm = fmaxf(tm, __shfl_xor(tm, 32));
      const float mn = fmaxf(m_, tm);
      const float sc = __expf(m_ - mn);
      m_ = mn;
      float rs = 0.0f;
#pragma unroll
      for (int r = 0; r < 16; ++r) {
        float e = __expf(sa[r] - mn);
        sa[r] = e;
        rs += e;
      }
      rs += __shfl_xor(rs, 32);
      l_ = l_ * sc + rs;
#pragma unroll
      for (int r = 0; r < 16; ++r) { oacc0[r] *= sc; oacc1[r] *= sc; }

      // ---- pack P -> bf16 B-fragments (cvt_pk pairs + permlane32_swap) ----
      unsigned a0 = pk2(sa[0],  sa[1]),  b0 = pk2(sa[4],  sa[5]);
      unsigned a1 = pk2(sa[2],  sa[3]),  b1 = pk2(sa[6],  sa[7]);
      unsigned a2 = pk2(sa[8],  sa[9]),  b2 = pk2(sa[12], sa[13]);
      unsigned a3 = pk2(sa[10], sa[11]), b3 = pk2(sa[14], sa[15]);
      asm volatile("v_permlane32_swap_b32 %0, %1" : "+v"(a0), "+v"(b0));
      asm volatile("v_permlane32_swap_b32 %0, %1" : "+v"(a1), "+v"(b1));
      asm volatile("v_permlane32_swap_b32 %0, %1" : "+v"(a2), "+v"(b2));
      asm volatile("v_permlane32_swap_b32 %0, %1" : "+v"(a3), "+v"(b3));
      union FU { unsigned u[4]; bf16x8 v; } f0, f1;
      f0.u[0] = a0; f0.u[1] = a1; f0.u[2] = b0; f0.u[3] = b1;  // k 0..15
      f1.u[0] = a2; f1.u[1] = a3; f1.u[2] = b2; f1.u[3] = b3;  // k 16..31

      // ---- PV: O^T[d][q] += V^T[d][k] * P^T[k][q] ----
      {
        char* vb0 = (char*)sm.kv.vt + l31 * 128;          // d-tile 0 rows
        char* vb1 = (char*)sm.kv.vt + (32 + l31) * 128;   // d-tile 1 rows
        int sw = (l31 & 7) << 4;   // (32+l31)&7 == l31&7
        int off0 = (kh * 64 + hi * 16) ^ sw;
        int off1 = (kh * 64 + 32 + hi * 16) ^ sw;
        bf16x8 v00 = *(const bf16x8*)(vb0 + off0);
        bf16x8 v01 = *(const bf16x8*)(vb0 + off1);
        bf16x8 v10 = *(const bf16x8*)(vb1 + off0);
        bf16x8 v11 = *(const bf16x8*)(vb1 + off1);
        oacc0 = __builtin_amdgcn_mfma_f32_32x32x16_bf16(v00, f0.v, oacc0, 0, 0, 0);
        oacc0 = __builtin_amdgcn_mfma_f32_32x32x16_bf16(v01, f1.v, oacc0, 0, 0, 0);
        oacc1 = __builtin_amdgcn_mfma_f32_32x32x16_bf16(v10, f0.v, oacc1, 0, 0, 0);
        oacc1 = __builtin_amdgcn_mfma_f32_32x32x16_bf16(v11, f1.v, oacc1, 0, 0, 0);
      }
    }  // kh
  }  // t

  // ---- epilogue: normalize, transpose via LDS, fp16 store ----
  __syncthreads();   // all waves done with kv before oep aliases it
  const float inv = 1.0f / l_;
#pragma unroll
  for (int g = 0; g < 4; ++g) {
    *(float4*)&sm.oep[w][l31][8 * g + 4 * hi] =
        make_float4(oacc0[4*g+0] * inv, oacc0[4*g+1] * inv,
                    oacc0[4*g+2] * inv, oacc0[4*g+3] * inv);
    *(float4*)&sm.oep[w][l31][8 * g + 4 * hi + 32] =
        make_float4(oacc1[4*g+0] * inv, oacc1[4*g+1] * inv,
                    oacc1[4*g+2] * inv, oacc1[4*g+3] * inv);
  }
  // same-wave readback: compiler orders via lgkmcnt, no barrier needed
  {
    int qr = lane >> 1, chh = lane & 1;
    const float* rp = &sm.oep[w][qr][chh * 32];
    const size_t base = (size_t)(qrow0 + w * 32 + qr) * D_MODEL + h * HD + chh * 32;
#pragma unroll
    for (int j = 0; j < 8; ++j) {
      float4 v = *(const float4*)(rp + j * 4);
      f16x4 o;
      o[0] = (_Float16)v.x; o[1] = (_Float16)v.y;
      o[2] = (_Float16)v.z; o[3] = (_Float16)v.w;
      *(f16x4*)(Of + base + j * 4) = o;
    }
  }
}

// ---------------------------------------------------------------------------
// Workspace layout (bytes):
//  [0,8M)    xf16   -> later Of16 (attn output)
//  [8M,10M)  wqf  [10,12) wkf  [12,14) wvf  [14,16) wof
//  [16M,24M) Qb (bf16)  [24,32) Kb  [32,40) Vb
// ---------------------------------------------------------------------------
extern "C" void kernel_launch(void* const* d_in, const int* in_sizes, int n_in,
                              void* d_out, int out_size, void* d_ws, size_t ws_size,
                              hipStream_t stream) {
  const float* x   = (const float*)d_in[0];
  const int*   pos = (const int*)d_in[1];
  const float* Wq  = (const float*)d_in[2];
  const float* Wk  = (const float*)d_in[3];
  const float* Wv  = (const float*)d_in[4];
  const float* Wo  = (const float*)d_in[5];
  float* out = (float*)d_out;

  char* ws = (char*)d_ws;
  const size_t MB = 1024 * 1024;
  _Float16* xf  = (_Float16*)(ws);
  _Float16* wqf = (_Float16*)(ws + 8 * MB);
  _Float16* wkf = (_Float16*)(ws + 10 * MB);
  _Float16* wvf = (_Float16*)(ws + 12 * MB);
  _Float16* wof = (_Float16*)(ws + 14 * MB);
  unsigned short* Qb = (unsigned short*)(ws + 16 * MB);
  unsigned short* Kb = (unsigned short*)(ws + 24 * MB);
  unsigned short* Vb = (unsigned short*)(ws + 32 * MB);
  _Float16* Of = xf;   // x dead after qkv_gemm

  dim3 blk(256);

  // fp16 conversions
  hipLaunchKernelGGL(cvt_f16, dim3(2048), blk, 0, stream, x, xf,
                     (int)((size_t)S_LEN * D_MODEL / 4));
  hipLaunchKernelGGL(cvt4_f16, dim3(512, 4), blk, 0, stream,
                     Wq, Wk, Wv, Wo, wqf, wkf, wvf, wof,
                     D_MODEL * D_MODEL / 4);

  // fused QKV projection + RoPE (Q scaled by 1/8), bf16 outputs
  hipLaunchKernelGGL(qkv_gemm, dim3(24, 32), blk, 0, stream,
                     xf, wqf, wkf, wvf, Qb, Kb, Vb, pos);

  // flash attention (writes fp16 O into xf region)
  hipLaunchKernelGGL(attn_mfma, dim3(512), blk, 0, stream, Qb, Kb, Vb, Of);

  // output projection, fp32 to d_out
  hipLaunchKernelGGL(out_gemm, dim3(8, 32), blk, 0, stream, Of, wof, out);
}

// Round 7
// 339.882 us; speedup vs baseline: 4.4609x; 1.0273x over previous
//
#include <hip/hip_runtime.h>
#include <hip/hip_bf16.h>
#include <math.h>

// Problem constants (B=1, S=4096, D=1024, H=16, hd=64)
#define S_LEN 4096
#define D_MODEL 1024
#define NHEAD 16
#define HD 64

typedef short bf16x8 __attribute__((ext_vector_type(8)));
typedef float f32x16 __attribute__((ext_vector_type(16)));
typedef _Float16 f16x8 __attribute__((ext_vector_type(8)));
typedef _Float16 f16x4 __attribute__((ext_vector_type(4)));

static __device__ __forceinline__ unsigned pk2(float lo, float hi) {
  __hip_bfloat162 h = __float22bfloat162_rn(make_float2(lo, hi));
  return *reinterpret_cast<unsigned*>(&h);
}

// async 16B global->LDS (wave-uniform LDS base + lane*16; per-lane global src)
static __device__ __forceinline__ void gload16(const void* g, void* l) {
  __builtin_amdgcn_global_load_lds(
      (const __attribute__((address_space(1))) unsigned*)g,
      (__attribute__((address_space(3))) unsigned*)l, 16, 0, 0);
}

// ---------------------------------------------------------------------------
// fp32 -> fp16 converts
// ---------------------------------------------------------------------------
__global__ __launch_bounds__(256)
void cvt_f16(const float* __restrict__ src, _Float16* __restrict__ dst, int n4) {
  for (int i = blockIdx.x * 256 + threadIdx.x; i < n4; i += gridDim.x * 256) {
    float4 v = ((const float4*)src)[i];
    f16x4 o;
    o[0] = (_Float16)v.x; o[1] = (_Float16)v.y;
    o[2] = (_Float16)v.z; o[3] = (_Float16)v.w;
    ((f16x4*)dst)[i] = o;
  }
}

__global__ __launch_bounds__(256)
void cvt4_f16(const float* __restrict__ s0, const float* __restrict__ s1,
              const float* __restrict__ s2, const float* __restrict__ s3,
              _Float16* __restrict__ d0, _Float16* __restrict__ d1,
              _Float16* __restrict__ d2, _Float16* __restrict__ d3, int n4) {
  const float* s = (blockIdx.y == 0) ? s0 : (blockIdx.y == 1) ? s1
                 : (blockIdx.y == 2) ? s2 : s3;
  _Float16* d = (blockIdx.y == 0) ? d0 : (blockIdx.y == 1) ? d1
              : (blockIdx.y == 2) ? d2 : d3;
  for (int i = blockIdx.x * 256 + threadIdx.x; i < n4; i += gridDim.x * 256) {
    float4 v = ((const float4*)s)[i];
    f16x4 o;
    o[0] = (_Float16)v.x; o[1] = (_Float16)v.y;
    o[2] = (_Float16)v.z; o[3] = (_Float16)v.w;
    ((f16x4*)d)[i] = o;
  }
}

// ---------------------------------------------------------------------------
// V transpose: V [4096][1024] bf16 -> Vt [1024][4096] bf16 (Vt[n][m]=V[m][n]).
// 64x64 tiles, LDS-bounced, coalesced both sides. grid (64, 16).
// ---------------------------------------------------------------------------
__global__ __launch_bounds__(256)
void vtrans(const unsigned short* __restrict__ V, unsigned short* __restrict__ Vt) {
  __shared__ unsigned short t[64][72];   // +8 pad, rows 144B (16B-aligned)
  const int tid = threadIdx.x;
  const int k0 = blockIdx.x * 64;
  const int n0 = blockIdx.y * 64;
#pragma unroll
  for (int p = 0; p < 2; ++p) {
    int idx = tid + p * 256;
    int r = idx >> 3, c8 = idx & 7;
    *(bf16x8*)&t[r][c8 * 8] =
        *(const bf16x8*)(V + (size_t)(k0 + r) * D_MODEL + n0 + c8 * 8);
  }
  __syncthreads();
  const int d = tid >> 2, kc = tid & 3;
  __align__(16) unsigned short buf[16];
#pragma unroll
  for (int j = 0; j < 16; ++j) buf[j] = t[kc * 16 + j][d];
  *(uint4*)(Vt + (size_t)(n0 + d) * S_LEN + k0 + kc * 16) = *(uint4*)buf;
  *(uint4*)(Vt + (size_t)(n0 + d) * S_LEN + k0 + kc * 16 + 8) = *(uint4*)(buf + 8);
}

// ---------------------------------------------------------------------------
// fp16 MFMA GEMM mainloop. C[m,n] = sum_k A[m,k]*B[n,k] (B row-major N x K).
// BM=128, BN=128, BK=32, 256 thr (4 waves 2x2), wave tile 64x64 (4 accs).
// Double-buffered LDS, proven 2-phase sync. Chunk-major LDS (conflict-free
// ds_read_b128 + linear gload_lds dest): unit(c,row) = c*128+row, c = k/8.
// ---------------------------------------------------------------------------
#define BUFBYTES 16384

static __device__ __forceinline__ void gemm_mainloop_f16(
    const _Float16* __restrict__ A, const _Float16* __restrict__ B,
    int tr0, int br0, char* ldsbuf, int tid,
    f32x16& acc00, f32x16& acc01, f32x16& acc10, f32x16& acc11) {
  const int lane = tid & 63, w = tid >> 6;
  const int l31 = lane & 31, hi5 = lane >> 5;
  const int wr = (w >> 1) * 64, wc = (w & 1) * 64;

  // staging: 16 units of 1024B; wave w owns ch = w + 4j (j=0..3)
  const _Float16* srcs[4];
  int offs[4];
#pragma unroll
  for (int j = 0; j < 4; ++j) {
    int ch = w + 4 * j;
    if (ch < 8) {            // A units
      int u = ch * 64 + lane;          // = c*128 + row
      srcs[j] = A + (size_t)(tr0 + (u & 127)) * 1024 + (u >> 7) * 8;
      offs[j] = ch * 1024;
    } else {                 // B units
      int u = (ch - 8) * 64 + lane;
      srcs[j] = B + (size_t)(br0 + (u & 127)) * 1024 + (u >> 7) * 8;
      offs[j] = 8192 + (ch - 8) * 1024;
    }
  }

#define STAGE(bufoff, koff)                                           \
  {                                                                   \
    _Pragma("unroll") for (int j = 0; j < 4; ++j)                     \
        gload16(srcs[j] + (koff), ldsbuf + (bufoff) + offs[j]);       \
  }

#define COMPUTE(bufoff)                                               \
  {                                                                   \
    const char* lb = ldsbuf + (bufoff);                               \
    _Pragma("unroll") for (int s = 0; s < 2; ++s) {                   \
      const int c = 2 * s + hi5;                                      \
      const char* pa = lb + (size_t)(c * 128 + wr + l31) * 16;        \
      f16x8 a0 = *(const f16x8*)(pa);                                 \
      f16x8 a1 = *(const f16x8*)(pa + 512);                           \
      const char* pb = lb + 8192 + (size_t)(c * 128 + wc + l31) * 16; \
      f16x8 b0 = *(const f16x8*)(pb);                                 \
      f16x8 b1 = *(const f16x8*)(pb + 512);                           \
      acc00 = __builtin_amdgcn_mfma_f32_32x32x16_f16(a0, b0, acc00, 0, 0, 0); \
      acc01 = __builtin_amdgcn_mfma_f32_32x32x16_f16(a0, b1, acc01, 0, 0, 0); \
      acc10 = __builtin_amdgcn_mfma_f32_32x32x16_f16(a1, b0, acc10, 0, 0, 0); \
      acc11 = __builtin_amdgcn_mfma_f32_32x32x16_f16(a1, b1, acc11, 0, 0, 0); \
    }                                                                 \
  }

  STAGE(0, 0);
  __syncthreads();   // syncthreads drains vmcnt(0) before s_barrier

#pragma unroll 1
  for (int it = 0; it < 16; ++it) {
    const int t0 = 2 * it;
    if (t0 < 31) STAGE(BUFBYTES, (t0 + 1) * 32);
    COMPUTE(0);
    __syncthreads();
    if (t0 + 1 < 31) STAGE(0, (t0 + 2) * 32);
    COMPUTE(BUFBYTES);
    __syncthreads();
  }
#undef STAGE
#undef COMPUTE
}

// ---------------------------------------------------------------------------
// Fused QKV projection GEMM + RoPE epilogue, bf16 outputs.
// Q pre-scaled by log2(e)/8 (softmax runs in exp2 domain).
// grid (24, 32): x = n-block (0..7 Q, 8..15 K, 16..23 V), y = m-block.
// ---------------------------------------------------------------------------
__global__ __launch_bounds__(256)
void qkv_gemm(const _Float16* __restrict__ xf,
              const _Float16* __restrict__ wqf, const _Float16* __restrict__ wkf,
              const _Float16* __restrict__ wvf,
              unsigned short* __restrict__ Qo, unsigned short* __restrict__ Ko,
              unsigned short* __restrict__ Vo, const int* __restrict__ pos) {
  __shared__ __align__(16) char ldsbuf[2 * BUFBYTES];
  const int tid = threadIdx.x;
  const int nb = blockIdx.x;
  const int which = nb >> 3;          // 0=Q 1=K 2=V
  const int br0 = (nb & 7) * 128;
  const int tr0 = blockIdx.y * 128;

  const _Float16* Bsrc = (which == 0) ? wqf : (which == 1) ? wkf : wvf;
  unsigned short* Out = (which == 0) ? Qo : (which == 1) ? Ko : Vo;

  f32x16 acc00, acc01, acc10, acc11;
#pragma unroll
  for (int r = 0; r < 16; ++r) {
    acc00[r] = 0.0f; acc01[r] = 0.0f; acc10[r] = 0.0f; acc11[r] = 0.0f;
  }

  gemm_mainloop_f16(xf, Bsrc, tr0, br0, ldsbuf, tid, acc00, acc01, acc10, acc11);

  // epilogue: RoPE (Q,K) + scale (Q: 1/8 * log2e) + bf16 pack/store
  const int lane = tid & 63, w = tid >> 6;
  const int l31 = lane & 31, hi5 = lane >> 5;
  const int wr = (w >> 1) * 64, wc = (w & 1) * 64;
  const float qs = (which == 0) ? 0.125f * 1.44269504088896f : 1.0f;

#pragma unroll
  for (int bc = 0; bc < 2; ++bc) {
    const int n = br0 + wc + bc * 32 + l31;   // output column 0..1023
    const int ch = n & 63;                    // channel within head
    const float fr = 1.0f / powf(10000.0f, (float)(ch & ~1) * (1.0f / 64.0f));
#pragma unroll
    for (int ar = 0; ar < 2; ++ar) {
      const f32x16& a = ar ? (bc ? acc11 : acc10) : (bc ? acc01 : acc00);
#pragma unroll
      for (int r = 0; r < 16; ++r) {
        const int m = tr0 + wr + ar * 32 + (r & 3) + 8 * (r >> 2) + 4 * hi5;
        float v = a[r];
        if (which < 2) {
          const float ang = (float)pos[m] * fr;
          float sn, cs;
          __sincosf(ang, &sn, &cs);
          const float vp = __shfl_xor(v, 1);
          v = (ch & 1) ? (vp * sn + v * cs) : (v * cs - vp * sn);
          v *= qs;
        }
        const float nv = __shfl_xor(v, 1);
        if ((ch & 1) == 0) {   // even lane writes the (even,odd) bf16 pair
          *(unsigned*)(Out + (size_t)m * 1024 + n) = pk2(v, nv);
        }
      }
    }
  }
}

// ---------------------------------------------------------------------------
// Output projection GEMM: out = O @ Wo^T, fp32 store. grid (8, 32).
// ---------------------------------------------------------------------------
__global__ __launch_bounds__(256)
void out_gemm(const _Float16* __restrict__ Of, const _Float16* __restrict__ Wof,
              float* __restrict__ out) {
  __shared__ __align__(16) char ldsbuf[2 * BUFBYTES];
  const int tid = threadIdx.x;
  const int br0 = blockIdx.x * 128;
  const int tr0 = blockIdx.y * 128;

  f32x16 acc00, acc01, acc10, acc11;
#pragma unroll
  for (int r = 0; r < 16; ++r) {
    acc00[r] = 0.0f; acc01[r] = 0.0f; acc10[r] = 0.0f; acc11[r] = 0.0f;
  }

  gemm_mainloop_f16(Of, Wof, tr0, br0, ldsbuf, tid, acc00, acc01, acc10, acc11);

  const int lane = tid & 63, w = tid >> 6;
  const int l31 = lane & 31, hi5 = lane >> 5;
  const int wr = (w >> 1) * 64, wc = (w & 1) * 64;
#pragma unroll
  for (int bc = 0; bc < 2; ++bc) {
    const int n = br0 + wc + bc * 32 + l31;
#pragma unroll
    for (int ar = 0; ar < 2; ++ar) {
      const f32x16& a = ar ? (bc ? acc11 : acc10) : (bc ? acc01 : acc00);
#pragma unroll
      for (int r = 0; r < 16; ++r) {
        const int m = tr0 + wr + ar * 32 + (r & 3) + 8 * (r >> 2) + 4 * hi5;
        out[(size_t)m * 1024 + n] = a[r];
      }
    }
  }
}

// ---------------------------------------------------------------------------
// bf16 MFMA flash attention (proven core). V consumed pre-transposed (Vt),
// staging identical in form to K (vector copies, same swizzled LDS image).
// Softmax in exp2 domain (Q pre-scaled by log2e/8) with defer-rescale THR=8.
// ---------------------------------------------------------------------------
union __align__(16) AttnSmem {
  unsigned short q[128 * 64];                                  // 16 KB
  struct { unsigned short k[64 * 64]; unsigned short vt[64 * 64]; } kv;  // 16 KB
  float oep[4][32][68];                                        // 34 KB
};

__global__ __launch_bounds__(256)
void attn_mfma(const unsigned short* __restrict__ Qg, const unsigned short* __restrict__ Kg,
               const unsigned short* __restrict__ Vt, _Float16* __restrict__ Of) {
  __shared__ AttnSmem sm;
  const int tid = threadIdx.x;
  const int lane = tid & 63;
  const int w = tid >> 6;
  const int h = blockIdx.x & 15;
  const int qb = 31 - (blockIdx.x >> 4);   // heavy blocks first
  const int qrow0 = qb * 128;
  const int l31 = lane & 31;
  const int hi = lane >> 5;

  // ---- stage Q tile (bf16, already scaled), swizzled ----
  {
    const unsigned short* src = Qg + (size_t)qrow0 * D_MODEL + h * HD;
#pragma unroll
    for (int p = 0; p < 4; ++p) {
      int idx = tid + p * 256;
      int row = idx >> 3, c8 = idx & 7;
      bf16x8 v = *(const bf16x8*)(src + (size_t)row * D_MODEL + c8 * 8);
      *(bf16x8*)((char*)sm.q + row * 128 + ((c8 * 16) ^ ((row & 7) << 4))) = v;
    }
  }
  __syncthreads();

  // ---- per-wave Q fragments held in registers (B-operand: col = q = lane&31)
  bf16x8 qf[4];
  {
    int qr = w * 32 + l31;
    char* rb = (char*)sm.q + qr * 128;
    int sw = (qr & 7) << 4;
#pragma unroll
    for (int s = 0; s < 4; ++s)
      qf[s] = *(const bf16x8*)(rb + ((s * 32 + hi * 16) ^ sw));
  }
  __syncthreads();

  f32x16 oacc0, oacc1;   // O^T: d-tiles 0 (d 0..31) and 1 (d 32..63)
#pragma unroll
  for (int r = 0; r < 16; ++r) { oacc0[r] = 0.0f; oacc1[r] = 0.0f; }
  float m_ = -1e30f, l_ = 0.0f;
  const int qg = qrow0 + w * 32 + l31;     // this lane's global q row
  const int qwmax = qrow0 + w * 32 + 31;   // wave's max q row
  const int nT = 2 * qb + 2;

  for (int t = 0; t < nT; ++t) {
    const int k0 = t * 64;
    __syncthreads();
    // ---- stage K rows and V^T rows (64x64 bf16 each), swizzled ----
    {
      const unsigned short* srcK = Kg + (size_t)k0 * D_MODEL + h * HD;
      const unsigned short* srcVt = Vt + (size_t)(h * HD) * S_LEN + k0;
#pragma unroll
      for (int p = 0; p < 2; ++p) {
        int idx = tid + p * 256;
        int row = idx >> 3, c8 = idx & 7;
        int sw = (c8 * 16) ^ ((row & 7) << 4);
        bf16x8 kv_ = *(const bf16x8*)(srcK + (size_t)row * D_MODEL + c8 * 8);
        *(bf16x8*)((char*)sm.kv.k + row * 128 + sw) = kv_;
        bf16x8 vv = *(const bf16x8*)(srcVt + (size_t)row * S_LEN + c8 * 8);
        *(bf16x8*)((char*)sm.kv.vt + row * 128 + sw) = vv;
      }
    }
    __syncthreads();

#pragma unroll
    for (int kh = 0; kh < 2; ++kh) {
      if (k0 + kh * 32 > qwmax) continue;   // wave-level causal skip

      // ---- QK^T: S^T[k][q], accumulate over 4 d-slices of 16 ----
      f32x16 sa;
#pragma unroll
      for (int r = 0; r < 16; ++r) sa[r] = 0.0f;
      {
        int krow = kh * 32 + l31;
        char* kb = (char*)sm.kv.k + krow * 128;
        int sw = (krow & 7) << 4;
#pragma unroll
        for (int s = 0; s < 4; ++s) {
          bf16x8 kf = *(const bf16x8*)(kb + ((s * 32 + hi * 16) ^ sw));
          sa = __builtin_amdgcn_mfma_f32_32x32x16_bf16(kf, qf[s], sa, 0, 0, 0);
        }
      }

      // ---- causal mask (only near the diagonal) ----
      if (k0 + kh * 32 + 31 > qg) {
#pragma unroll
        for (int r = 0; r < 16; ++r) {
          int kg = k0 + kh * 32 + (r & 3) + 8 * (r >> 2) + 4 * hi;
          if (kg > qg) sa[r] = -1e30f;
        }
      }

      // ---- online softmax (exp2 domain), defer-rescale THR=8 ----
      float tm = sa[0];
#pragma unroll
      for (int r = 1; r < 16; ++r) tm = fmaxf(tm, sa[r]);
      tm = fmaxf(tm, __shfl_xor(tm, 32));
      if (!__all(tm <= m_ + 8.0f)) {
        const float mn = fmaxf(m_, tm);
        const float sc = exp2f(m_ - mn);
        m_ = mn;
        l_ *= sc;
#pragma unroll
        for (int r = 0; r < 16; ++r) { oacc0[r] *= sc; oacc1[r] *= sc; }
      }
      float rs = 0.0f;
#pragma unroll
      for (int r = 0; r < 16; ++r) {
        float e = exp2f(sa[r] - m_);
        sa[r] = e;
        rs += e;
      }
      rs += __shfl_xor(rs, 32);
      l_ += rs;

      // ---- pack P -> bf16 B-fragments (cvt_pk pairs + permlane32_swap) ----
      unsigned a0 = pk2(sa[0],  sa[1]),  b0 = pk2(sa[4],  sa[5]);
      unsigned a1 = pk2(sa[2],  sa[3]),  b1 = pk2(sa[6],  sa[7]);
      unsigned a2 = pk2(sa[8],  sa[9]),  b2 = pk2(sa[12], sa[13]);
      unsigned a3 = pk2(sa[10], sa[11]), b3 = pk2(sa[14], sa[15]);
      asm volatile("v_permlane32_swap_b32 %0, %1" : "+v"(a0), "+v"(b0));
      asm volatile("v_permlane32_swap_b32 %0, %1" : "+v"(a1), "+v"(b1));
      asm volatile("v_permlane32_swap_b32 %0, %1" : "+v"(a2), "+v"(b2));
      asm volatile("v_permlane32_swap_b32 %0, %1" : "+v"(a3), "+v"(b3));
      union FU { unsigned u[4]; bf16x8 v; } f0, f1;
      f0.u[0] = a0; f0.u[1] = a1; f0.u[2] = b0; f0.u[3] = b1;  // k 0..15
      f1.u[0] = a2; f1.u[1] = a3; f1.u[2] = b2; f1.u[3] = b3;  // k 16..31

      // ---- PV: O^T[d][q] += V^T[d][k] * P^T[k][q] ----
      {
        char* vb0 = (char*)sm.kv.vt + l31 * 128;          // d-tile 0 rows
        char* vb1 = (char*)sm.kv.vt + (32 + l31) * 128;   // d-tile 1 rows
        int sw = (l31 & 7) << 4;   // (32+l31)&7 == l31&7
        int off0 = (kh * 64 + hi * 16) ^ sw;
        int off1 = (kh * 64 + 32 + hi * 16) ^ sw;
        bf16x8 v00 = *(const bf16x8*)(vb0 + off0);
        bf16x8 v01 = *(const bf16x8*)(vb0 + off1);
        bf16x8 v10 = *(const bf16x8*)(vb1 + off0);
        bf16x8 v11 = *(const bf16x8*)(vb1 + off1);
        oacc0 = __builtin_amdgcn_mfma_f32_32x32x16_bf16(v00, f0.v, oacc0, 0, 0, 0);
        oacc0 = __builtin_amdgcn_mfma_f32_32x32x16_bf16(v01, f1.v, oacc0, 0, 0, 0);
        oacc1 = __builtin_amdgcn_mfma_f32_32x32x16_bf16(v10, f0.v, oacc1, 0, 0, 0);
        oacc1 = __builtin_amdgcn_mfma_f32_32x32x16_bf16(v11, f1.v, oacc1, 0, 0, 0);
      }
    }  // kh
  }  // t

  // ---- epilogue: normalize, transpose via LDS, fp16 store ----
  __syncthreads();   // all waves done with kv before oep aliases it
  const float inv = 1.0f / l_;
#pragma unroll
  for (int g = 0; g < 4; ++g) {
    *(float4*)&sm.oep[w][l31][8 * g + 4 * hi] =
        make_float4(oacc0[4*g+0] * inv, oacc0[4*g+1] * inv,
                    oacc0[4*g+2] * inv, oacc0[4*g+3] * inv);
    *(float4*)&sm.oep[w][l31][8 * g + 4 * hi + 32] =
        make_float4(oacc1[4*g+0] * inv, oacc1[4*g+1] * inv,
                    oacc1[4*g+2] * inv, oacc1[4*g+3] * inv);
  }
  // same-wave readback: compiler orders via lgkmcnt, no barrier needed
  {
    int qr = lane >> 1, chh = lane & 1;
    const float* rp = &sm.oep[w][qr][chh * 32];
    const size_t base = (size_t)(qrow0 + w * 32 + qr) * D_MODEL + h * HD + chh * 32;
#pragma unroll
    for (int j = 0; j < 8; ++j) {
      float4 v = *(const float4*)(rp + j * 4);
      f16x4 o;
      o[0] = (_Float16)v.x; o[1] = (_Float16)v.y;
      o[2] = (_Float16)v.z; o[3] = (_Float16)v.w;
      *(f16x4*)(Of + base + j * 4) = o;
    }
  }
}

// ---------------------------------------------------------------------------
// Workspace layout (bytes):
//  [0,8M)    xf16   -> later Of16 (attn output)
//  [8M,10M)  wqf  [10,12) wkf  [12,14) wvf  [14,16) wof
//  [16M,24M) Qb (bf16)  [24,32) Kb  [32,40) Vb  [40,48) Vt
// ---------------------------------------------------------------------------
extern "C" void kernel_launch(void* const* d_in, const int* in_sizes, int n_in,
                              void* d_out, int out_size, void* d_ws, size_t ws_size,
                              hipStream_t stream) {
  const float* x   = (const float*)d_in[0];
  const int*   pos = (const int*)d_in[1];
  const float* Wq  = (const float*)d_in[2];
  const float* Wk  = (const float*)d_in[3];
  const float* Wv  = (const float*)d_in[4];
  const float* Wo  = (const float*)d_in[5];
  float* out = (float*)d_out;

  char* ws = (char*)d_ws;
  const size_t MB = 1024 * 1024;
  _Float16* xf  = (_Float16*)(ws);
  _Float16* wqf = (_Float16*)(ws + 8 * MB);
  _Float16* wkf = (_Float16*)(ws + 10 * MB);
  _Float16* wvf = (_Float16*)(ws + 12 * MB);
  _Float16* wof = (_Float16*)(ws + 14 * MB);
  unsigned short* Qb = (unsigned short*)(ws + 16 * MB);
  unsigned short* Kb = (unsigned short*)(ws + 24 * MB);
  unsigned short* Vb = (unsigned short*)(ws + 32 * MB);
  unsigned short* Vt = (unsigned short*)(ws + 40 * MB);
  _Float16* Of = xf;   // x dead after qkv_gemm

  dim3 blk(256);

  // fp16 conversions
  hipLaunchKernelGGL(cvt_f16, dim3(2048), blk, 0, stream, x, xf,
                     (int)((size_t)S_LEN * D_MODEL / 4));
  hipLaunchKernelGGL(cvt4_f16, dim3(512, 4), blk, 0, stream,
                     Wq, Wk, Wv, Wo, wqf, wkf, wvf, wof,
                     D_MODEL * D_MODEL / 4);

  // fused QKV projection + RoPE (Q scaled by log2e/8), bf16 outputs
  hipLaunchKernelGGL(qkv_gemm, dim3(24, 32), blk, 0, stream,
                     xf, wqf, wkf, wvf, Qb, Kb, Vb, pos);

  // V transpose for conflict-free attention staging
  hipLaunchKernelGGL(vtrans, dim3(64, 16), blk, 0, stream, Vb, Vt);

  // flash attention (writes fp16 O into xf region)
  hipLaunchKernelGGL(attn_mfma, dim3(512), blk, 0, stream, Qb, Kb, Vt, Of);

  // output projection, fp32 to d_out
  hipLaunchKernelGGL(out_gemm, dim3(8, 32), blk, 0, stream, Of, wof, out);
}

// Round 8
// 326.675 us; speedup vs baseline: 4.6412x; 1.0404x over previous
//
#include <hip/hip_runtime.h>
#include <hip/hip_bf16.h>
#include <math.h>

// Problem constants (B=1, S=4096, D=1024, H=16, hd=64)
#define S_LEN 4096
#define D_MODEL 1024
#define NHEAD 16
#define HD 64

typedef short bf16x8 __attribute__((ext_vector_type(8)));
typedef float f32x16 __attribute__((ext_vector_type(16)));
typedef _Float16 f16x8 __attribute__((ext_vector_type(8)));
typedef _Float16 f16x4 __attribute__((ext_vector_type(4)));

static __device__ __forceinline__ unsigned pk2(float lo, float hi) {
  __hip_bfloat162 h = __float22bfloat162_rn(make_float2(lo, hi));
  return *reinterpret_cast<unsigned*>(&h);
}

// async 16B global->LDS (wave-uniform LDS base + lane*16; per-lane global src)
static __device__ __forceinline__ void gload16(const void* g, void* l) {
  __builtin_amdgcn_global_load_lds(
      (const __attribute__((address_space(1))) unsigned*)g,
      (__attribute__((address_space(3))) unsigned*)l, 16, 0, 0);
}

// ---------------------------------------------------------------------------
// fp32 -> fp16 converts
// ---------------------------------------------------------------------------
__global__ __launch_bounds__(256)
void cvt_f16(const float* __restrict__ src, _Float16* __restrict__ dst, int n4) {
  for (int i = blockIdx.x * 256 + threadIdx.x; i < n4; i += gridDim.x * 256) {
    float4 v = ((const float4*)src)[i];
    f16x4 o;
    o[0] = (_Float16)v.x; o[1] = (_Float16)v.y;
    o[2] = (_Float16)v.z; o[3] = (_Float16)v.w;
    ((f16x4*)dst)[i] = o;
  }
}

__global__ __launch_bounds__(256)
void cvt4_f16(const float* __restrict__ s0, const float* __restrict__ s1,
              const float* __restrict__ s2, const float* __restrict__ s3,
              _Float16* __restrict__ d0, _Float16* __restrict__ d1,
              _Float16* __restrict__ d2, _Float16* __restrict__ d3, int n4) {
  const float* s = (blockIdx.y == 0) ? s0 : (blockIdx.y == 1) ? s1
                 : (blockIdx.y == 2) ? s2 : s3;
  _Float16* d = (blockIdx.y == 0) ? d0 : (blockIdx.y == 1) ? d1
              : (blockIdx.y == 2) ? d2 : d3;
  for (int i = blockIdx.x * 256 + threadIdx.x; i < n4; i += gridDim.x * 256) {
    float4 v = ((const float4*)s)[i];
    f16x4 o;
    o[0] = (_Float16)v.x; o[1] = (_Float16)v.y;
    o[2] = (_Float16)v.z; o[3] = (_Float16)v.w;
    ((f16x4*)d)[i] = o;
  }
}

// ---------------------------------------------------------------------------
// V transpose: V [4096][1024] bf16 -> Vt [1024][4096] bf16 (Vt[n][m]=V[m][n]).
// 64x64 tiles, LDS-bounced, coalesced both sides. grid (64, 16).
// ---------------------------------------------------------------------------
__global__ __launch_bounds__(256)
void vtrans(const unsigned short* __restrict__ V, unsigned short* __restrict__ Vt) {
  __shared__ unsigned short t[64][72];   // +8 pad, rows 144B (16B-aligned)
  const int tid = threadIdx.x;
  const int k0 = blockIdx.x * 64;
  const int n0 = blockIdx.y * 64;
#pragma unroll
  for (int p = 0; p < 2; ++p) {
    int idx = tid + p * 256;
    int r = idx >> 3, c8 = idx & 7;
    *(bf16x8*)&t[r][c8 * 8] =
        *(const bf16x8*)(V + (size_t)(k0 + r) * D_MODEL + n0 + c8 * 8);
  }
  __syncthreads();
  const int d = tid >> 2, kc = tid & 3;
  __align__(16) unsigned short buf[16];
#pragma unroll
  for (int j = 0; j < 16; ++j) buf[j] = t[kc * 16 + j][d];
  *(uint4*)(Vt + (size_t)(n0 + d) * S_LEN + k0 + kc * 16) = *(uint4*)buf;
  *(uint4*)(Vt + (size_t)(n0 + d) * S_LEN + k0 + kc * 16 + 8) = *(uint4*)(buf + 8);
}

// ---------------------------------------------------------------------------
// fp16 MFMA GEMM mainloop. C[m,n] = sum_k A[m,k]*B[n,k] (B row-major N x K).
// BM=128, BN=128, BK=32, 256 thr (4 waves 2x2), wave tile 64x64 (4 accs).
// Double-buffered LDS, proven 2-phase sync. Chunk-major LDS (conflict-free
// ds_read_b128 + linear gload_lds dest): unit(c,row) = c*128+row, c = k/8.
// ---------------------------------------------------------------------------
#define BUFBYTES 16384

static __device__ __forceinline__ void gemm_mainloop_f16(
    const _Float16* __restrict__ A, const _Float16* __restrict__ B,
    int tr0, int br0, char* ldsbuf, int tid,
    f32x16& acc00, f32x16& acc01, f32x16& acc10, f32x16& acc11) {
  const int lane = tid & 63, w = tid >> 6;
  const int l31 = lane & 31, hi5 = lane >> 5;
  const int wr = (w >> 1) * 64, wc = (w & 1) * 64;

  // staging: 16 units of 1024B; wave w owns ch = w + 4j (j=0..3)
  const _Float16* srcs[4];
  int offs[4];
#pragma unroll
  for (int j = 0; j < 4; ++j) {
    int ch = w + 4 * j;
    if (ch < 8) {            // A units
      int u = ch * 64 + lane;          // = c*128 + row
      srcs[j] = A + (size_t)(tr0 + (u & 127)) * 1024 + (u >> 7) * 8;
      offs[j] = ch * 1024;
    } else {                 // B units
      int u = (ch - 8) * 64 + lane;
      srcs[j] = B + (size_t)(br0 + (u & 127)) * 1024 + (u >> 7) * 8;
      offs[j] = 8192 + (ch - 8) * 1024;
    }
  }

#define STAGE(bufoff, koff)                                           \
  {                                                                   \
    _Pragma("unroll") for (int j = 0; j < 4; ++j)                     \
        gload16(srcs[j] + (koff), ldsbuf + (bufoff) + offs[j]);       \
  }

#define COMPUTE(bufoff)                                               \
  {                                                                   \
    const char* lb = ldsbuf + (bufoff);                               \
    _Pragma("unroll") for (int s = 0; s < 2; ++s) {                   \
      const int c = 2 * s + hi5;                                      \
      const char* pa = lb + (size_t)(c * 128 + wr + l31) * 16;        \
      f16x8 a0 = *(const f16x8*)(pa);                                 \
      f16x8 a1 = *(const f16x8*)(pa + 512);                           \
      const char* pb = lb + 8192 + (size_t)(c * 128 + wc + l31) * 16; \
      f16x8 b0 = *(const f16x8*)(pb);                                 \
      f16x8 b1 = *(const f16x8*)(pb + 512);                           \
      acc00 = __builtin_amdgcn_mfma_f32_32x32x16_f16(a0, b0, acc00, 0, 0, 0); \
      acc01 = __builtin_amdgcn_mfma_f32_32x32x16_f16(a0, b1, acc01, 0, 0, 0); \
      acc10 = __builtin_amdgcn_mfma_f32_32x32x16_f16(a1, b0, acc10, 0, 0, 0); \
      acc11 = __builtin_amdgcn_mfma_f32_32x32x16_f16(a1, b1, acc11, 0, 0, 0); \
    }                                                                 \
  }

  STAGE(0, 0);
  __syncthreads();   // syncthreads drains vmcnt(0) before s_barrier

#pragma unroll 1
  for (int it = 0; it < 16; ++it) {
    const int t0 = 2 * it;
    if (t0 < 31) STAGE(BUFBYTES, (t0 + 1) * 32);
    COMPUTE(0);
    __syncthreads();
    if (t0 + 1 < 31) STAGE(0, (t0 + 2) * 32);
    COMPUTE(BUFBYTES);
    __syncthreads();
  }
#undef STAGE
#undef COMPUTE
}

// ---------------------------------------------------------------------------
// Fused QKV projection GEMM + RoPE epilogue, bf16 outputs.
// Q pre-scaled by log2(e)/8 (softmax runs in exp2 domain).
// grid (24, 32): x = n-block (0..7 Q, 8..15 K, 16..23 V), y = m-block.
// ---------------------------------------------------------------------------
__global__ __launch_bounds__(256)
void qkv_gemm(const _Float16* __restrict__ xf,
              const _Float16* __restrict__ wqf, const _Float16* __restrict__ wkf,
              const _Float16* __restrict__ wvf,
              unsigned short* __restrict__ Qo, unsigned short* __restrict__ Ko,
              unsigned short* __restrict__ Vo, const int* __restrict__ pos) {
  __shared__ __align__(16) char ldsbuf[2 * BUFBYTES];
  const int tid = threadIdx.x;
  const int nb = blockIdx.x;
  const int which = nb >> 3;          // 0=Q 1=K 2=V
  const int br0 = (nb & 7) * 128;
  const int tr0 = blockIdx.y * 128;

  const _Float16* Bsrc = (which == 0) ? wqf : (which == 1) ? wkf : wvf;
  unsigned short* Out = (which == 0) ? Qo : (which == 1) ? Ko : Vo;

  f32x16 acc00, acc01, acc10, acc11;
#pragma unroll
  for (int r = 0; r < 16; ++r) {
    acc00[r] = 0.0f; acc01[r] = 0.0f; acc10[r] = 0.0f; acc11[r] = 0.0f;
  }

  gemm_mainloop_f16(xf, Bsrc, tr0, br0, ldsbuf, tid, acc00, acc01, acc10, acc11);

  // epilogue: RoPE (Q,K) + scale (Q: 1/8 * log2e) + bf16 pack/store
  const int lane = tid & 63, w = tid >> 6;
  const int l31 = lane & 31, hi5 = lane >> 5;
  const int wr = (w >> 1) * 64, wc = (w & 1) * 64;
  const float qs = (which == 0) ? 0.125f * 1.44269504088896f : 1.0f;

#pragma unroll
  for (int bc = 0; bc < 2; ++bc) {
    const int n = br0 + wc + bc * 32 + l31;   // output column 0..1023
    const int ch = n & 63;                    // channel within head
    const float fr = 1.0f / powf(10000.0f, (float)(ch & ~1) * (1.0f / 64.0f));
#pragma unroll
    for (int ar = 0; ar < 2; ++ar) {
      const f32x16& a = ar ? (bc ? acc11 : acc10) : (bc ? acc01 : acc00);
#pragma unroll
      for (int r = 0; r < 16; ++r) {
        const int m = tr0 + wr + ar * 32 + (r & 3) + 8 * (r >> 2) + 4 * hi5;
        float v = a[r];
        if (which < 2) {
          const float ang = (float)pos[m] * fr;
          float sn, cs;
          __sincosf(ang, &sn, &cs);
          const float vp = __shfl_xor(v, 1);
          v = (ch & 1) ? (vp * sn + v * cs) : (v * cs - vp * sn);
          v *= qs;
        }
        const float nv = __shfl_xor(v, 1);
        if ((ch & 1) == 0) {   // even lane writes the (even,odd) bf16 pair
          *(unsigned*)(Out + (size_t)m * 1024 + n) = pk2(v, nv);
        }
      }
    }
  }
}

// ---------------------------------------------------------------------------
// Output projection GEMM: out = O @ Wo^T, fp32 store. grid (8, 32).
// ---------------------------------------------------------------------------
__global__ __launch_bounds__(256)
void out_gemm(const _Float16* __restrict__ Of, const _Float16* __restrict__ Wof,
              float* __restrict__ out) {
  __shared__ __align__(16) char ldsbuf[2 * BUFBYTES];
  const int tid = threadIdx.x;
  const int br0 = blockIdx.x * 128;
  const int tr0 = blockIdx.y * 128;

  f32x16 acc00, acc01, acc10, acc11;
#pragma unroll
  for (int r = 0; r < 16; ++r) {
    acc00[r] = 0.0f; acc01[r] = 0.0f; acc10[r] = 0.0f; acc11[r] = 0.0f;
  }

  gemm_mainloop_f16(Of, Wof, tr0, br0, ldsbuf, tid, acc00, acc01, acc10, acc11);

  const int lane = tid & 63, w = tid >> 6;
  const int l31 = lane & 31, hi5 = lane >> 5;
  const int wr = (w >> 1) * 64, wc = (w & 1) * 64;
#pragma unroll
  for (int bc = 0; bc < 2; ++bc) {
    const int n = br0 + wc + bc * 32 + l31;
#pragma unroll
    for (int ar = 0; ar < 2; ++ar) {
      const f32x16& a = ar ? (bc ? acc11 : acc10) : (bc ? acc01 : acc00);
#pragma unroll
      for (int r = 0; r < 16; ++r) {
        const int m = tr0 + wr + ar * 32 + (r & 3) + 8 * (r >> 2) + 4 * hi5;
        out[(size_t)m * 1024 + n] = a[r];
      }
    }
  }
}

// ---------------------------------------------------------------------------
// bf16 MFMA flash attention (proven core) + T14 async register prefetch:
// tile t+1's K/Vt global loads issue right after tile t's ds_write, hiding
// HBM latency under tile t's compute. Two named reg sets (A/B), 2 tiles per
// loop iteration (nT always even). T5 setprio around MFMA clusters.
// Softmax in exp2 domain (Q pre-scaled by log2e/8) with defer-rescale THR=8.
// ---------------------------------------------------------------------------
union __align__(16) AttnSmem {
  unsigned short q[128 * 64];                                  // 16 KB
  struct { unsigned short k[64 * 64]; unsigned short vt[64 * 64]; } kv;  // 16 KB
  float oep[4][32][68];                                        // 34 KB
};

__global__ __launch_bounds__(256)
void attn_mfma(const unsigned short* __restrict__ Qg, const unsigned short* __restrict__ Kg,
               const unsigned short* __restrict__ Vt, _Float16* __restrict__ Of) {
  __shared__ AttnSmem sm;
  const int tid = threadIdx.x;
  const int lane = tid & 63;
  const int w = tid >> 6;
  const int h = blockIdx.x & 15;
  const int qb = 31 - (blockIdx.x >> 4);   // heavy blocks first
  const int qrow0 = qb * 128;
  const int l31 = lane & 31;
  const int hi = lane >> 5;

  // ---- stage Q tile (bf16, already scaled), swizzled ----
  {
    const unsigned short* src = Qg + (size_t)qrow0 * D_MODEL + h * HD;
#pragma unroll
    for (int p = 0; p < 4; ++p) {
      int idx = tid + p * 256;
      int row = idx >> 3, c8 = idx & 7;
      bf16x8 v = *(const bf16x8*)(src + (size_t)row * D_MODEL + c8 * 8);
      *(bf16x8*)((char*)sm.q + row * 128 + ((c8 * 16) ^ ((row & 7) << 4))) = v;
    }
  }
  __syncthreads();

  // ---- per-wave Q fragments held in registers (B-operand: col = q = lane&31)
  bf16x8 qf[4];
  {
    int qr = w * 32 + l31;
    char* rb = (char*)sm.q + qr * 128;
    int sw = (qr & 7) << 4;
#pragma unroll
    for (int s = 0; s < 4; ++s)
      qf[s] = *(const bf16x8*)(rb + ((s * 32 + hi * 16) ^ sw));
  }
  __syncthreads();   // all qf loaded before kv (aliases q) is written

  f32x16 oacc0, oacc1;   // O^T: d-tiles 0 (d 0..31) and 1 (d 32..63)
#pragma unroll
  for (int r = 0; r < 16; ++r) { oacc0[r] = 0.0f; oacc1[r] = 0.0f; }
  float m_ = -1e30f, l_ = 0.0f;
  const int qg = qrow0 + w * 32 + l31;     // this lane's global q row
  const int qwmax = qrow0 + w * 32 + 31;   // wave's max q row
  const int nT = 2 * qb + 2;               // always even

  // staging geometry: thread stages rows sr0 (p=0) and sr0+32 (p=1), chunk sc0
  const int sr0 = tid >> 3, sc0 = tid & 7;
  const int sr1 = sr0 + 32;                // (sr1&7)==(sr0&7) -> same swizzle
  const int swz = (sc0 * 16) ^ ((sr0 & 7) << 4);
  const unsigned short* srcK = Kg + h * HD;
  const unsigned short* srcVt = Vt + (size_t)(h * HD) * S_LEN;

  bf16x8 kA0, kA1, vA0, vA1, kB0, kB1, vB0, vB1;

#define LOADKV(K0, K1, V0, V1, t)                                        \
  if ((t) < nT) {                                                        \
    const int kk = (t) * 64;                                             \
    K0 = *(const bf16x8*)(srcK + (size_t)(kk + sr0) * D_MODEL + sc0 * 8);\
    K1 = *(const bf16x8*)(srcK + (size_t)(kk + sr1) * D_MODEL + sc0 * 8);\
    V0 = *(const bf16x8*)(srcVt + (size_t)sr0 * S_LEN + kk + sc0 * 8);   \
    V1 = *(const bf16x8*)(srcVt + (size_t)sr1 * S_LEN + kk + sc0 * 8);   \
  }

#define WRITEKV(K0, K1, V0, V1)                                          \
  {                                                                      \
    *(bf16x8*)((char*)sm.kv.k + sr0 * 128 + swz) = K0;                   \
    *(bf16x8*)((char*)sm.kv.k + sr1 * 128 + swz) = K1;                   \
    *(bf16x8*)((char*)sm.kv.vt + sr0 * 128 + swz) = V0;                  \
    *(bf16x8*)((char*)sm.kv.vt + sr1 * 128 + swz) = V1;                  \
  }

  // one K/V tile: QK^T -> online softmax -> pack -> PV, for both kh halves
#define COMPUTE_TILE(t)                                                  \
  {                                                                      \
    const int k0 = (t) * 64;                                             \
    _Pragma("unroll") for (int kh = 0; kh < 2; ++kh) {                   \
      if (k0 + kh * 32 > qwmax) continue;                                \
      f32x16 sa;                                                         \
      _Pragma("unroll") for (int r = 0; r < 16; ++r) sa[r] = 0.0f;       \
      {                                                                  \
        int krow = kh * 32 + l31;                                        \
        char* kb = (char*)sm.kv.k + krow * 128;                          \
        int sw = (krow & 7) << 4;                                        \
        __builtin_amdgcn_s_setprio(1);                                   \
        _Pragma("unroll") for (int s = 0; s < 4; ++s) {                  \
          bf16x8 kf = *(const bf16x8*)(kb + ((s * 32 + hi * 16) ^ sw));  \
          sa = __builtin_amdgcn_mfma_f32_32x32x16_bf16(kf, qf[s], sa, 0, 0, 0); \
        }                                                                \
        __builtin_amdgcn_s_setprio(0);                                   \
      }                                                                  \
      if (k0 + kh * 32 + 31 > qg) {                                      \
        _Pragma("unroll") for (int r = 0; r < 16; ++r) {                 \
          int kg = k0 + kh * 32 + (r & 3) + 8 * (r >> 2) + 4 * hi;       \
          if (kg > qg) sa[r] = -1e30f;                                   \
        }                                                                \
      }                                                                  \
      /* row max via max3-fusable tree */                                \
      float x0 = fmaxf(fmaxf(sa[0], sa[1]), sa[2]);                      \
      float x1 = fmaxf(fmaxf(sa[3], sa[4]), sa[5]);                      \
      float x2 = fmaxf(fmaxf(sa[6], sa[7]), sa[8]);                      \
      float x3 = fmaxf(fmaxf(sa[9], sa[10]), sa[11]);                    \
      float x4 = fmaxf(fmaxf(sa[12], sa[13]), sa[14]);                   \
      float tm = fmaxf(fmaxf(x0, x1), x2);                               \
      tm = fmaxf(fmaxf(tm, x3), x4);                                     \
      tm = fmaxf(tm, sa[15]);                                            \
      tm = fmaxf(tm, __shfl_xor(tm, 32));                                \
      if (!__all(tm <= m_ + 8.0f)) {                                     \
        const float mn = fmaxf(m_, tm);                                  \
        const float sc = exp2f(m_ - mn);                                 \
        m_ = mn;                                                         \
        l_ *= sc;                                                        \
        _Pragma("unroll") for (int r = 0; r < 16; ++r) {                 \
          oacc0[r] *= sc; oacc1[r] *= sc;                                \
        }                                                                \
      }                                                                  \
      float rs = 0.0f;                                                   \
      _Pragma("unroll") for (int r = 0; r < 16; ++r) {                   \
        float e = exp2f(sa[r] - m_);                                     \
        sa[r] = e;                                                       \
        rs += e;                                                         \
      }                                                                  \
      rs += __shfl_xor(rs, 32);                                          \
      l_ += rs;                                                          \
      unsigned a0 = pk2(sa[0], sa[1]),  b0 = pk2(sa[4], sa[5]);          \
      unsigned a1 = pk2(sa[2], sa[3]),  b1 = pk2(sa[6], sa[7]);          \
      unsigned a2 = pk2(sa[8], sa[9]),  b2 = pk2(sa[12], sa[13]);        \
      unsigned a3 = pk2(sa[10], sa[11]), b3 = pk2(sa[14], sa[15]);       \
      asm volatile("v_permlane32_swap_b32 %0, %1" : "+v"(a0), "+v"(b0)); \
      asm volatile("v_permlane32_swap_b32 %0, %1" : "+v"(a1), "+v"(b1)); \
      asm volatile("v_permlane32_swap_b32 %0, %1" : "+v"(a2), "+v"(b2)); \
      asm volatile("v_permlane32_swap_b32 %0, %1" : "+v"(a3), "+v"(b3)); \
      union FU { unsigned u[4]; bf16x8 v; } f0, f1;                      \
      f0.u[0] = a0; f0.u[1] = a1; f0.u[2] = b0; f0.u[3] = b1;            \
      f1.u[0] = a2; f1.u[1] = a3; f1.u[2] = b2; f1.u[3] = b3;            \
      {                                                                  \
        char* vb0 = (char*)sm.kv.vt + l31 * 128;                         \
        char* vb1 = (char*)sm.kv.vt + (32 + l31) * 128;                  \
        int sw = (l31 & 7) << 4;                                         \
        int off0 = (kh * 64 + hi * 16) ^ sw;                             \
        int off1 = (kh * 64 + 32 + hi * 16) ^ sw;                        \
        bf16x8 v00 = *(const bf16x8*)(vb0 + off0);                       \
        bf16x8 v01 = *(const bf16x8*)(vb0 + off1);                       \
        bf16x8 v10 = *(const bf16x8*)(vb1 + off0);                       \
        bf16x8 v11 = *(const bf16x8*)(vb1 + off1);                       \
        __builtin_amdgcn_s_setprio(1);                                   \
        oacc0 = __builtin_amdgcn_mfma_f32_32x32x16_bf16(v00, f0.v, oacc0, 0, 0, 0); \
        oacc0 = __builtin_amdgcn_mfma_f32_32x32x16_bf16(v01, f1.v, oacc0, 0, 0, 0); \
        oacc1 = __builtin_amdgcn_mfma_f32_32x32x16_bf16(v10, f0.v, oacc1, 0, 0, 0); \
        oacc1 = __builtin_amdgcn_mfma_f32_32x32x16_bf16(v11, f1.v, oacc1, 0, 0, 0); \
        __builtin_amdgcn_s_setprio(0);                                   \
      }                                                                  \
    }                                                                    \
  }

  LOADKV(kA0, kA1, vA0, vA1, 0);

#pragma unroll 1
  for (int tt = 0; tt < nT; tt += 2) {
    __syncthreads();                       // prev compute done with LDS
    WRITEKV(kA0, kA1, vA0, vA1);
    LOADKV(kB0, kB1, vB0, vB1, tt + 1);    // in flight during compute(tt)
    __syncthreads();                       // tile tt ready
    COMPUTE_TILE(tt);
    __syncthreads();
    WRITEKV(kB0, kB1, vB0, vB1);
    LOADKV(kA0, kA1, vA0, vA1, tt + 2);    // in flight during compute(tt+1)
    __syncthreads();
    COMPUTE_TILE(tt + 1);
  }
#undef LOADKV
#undef WRITEKV
#undef COMPUTE_TILE

  // ---- epilogue: normalize, transpose via LDS, fp16 store ----
  __syncthreads();   // all waves done with kv before oep aliases it
  const float inv = 1.0f / l_;
#pragma unroll
  for (int g = 0; g < 4; ++g) {
    *(float4*)&sm.oep[w][l31][8 * g + 4 * hi] =
        make_float4(oacc0[4*g+0] * inv, oacc0[4*g+1] * inv,
                    oacc0[4*g+2] * inv, oacc0[4*g+3] * inv);
    *(float4*)&sm.oep[w][l31][8 * g + 4 * hi + 32] =
        make_float4(oacc1[4*g+0] * inv, oacc1[4*g+1] * inv,
                    oacc1[4*g+2] * inv, oacc1[4*g+3] * inv);
  }
  // same-wave readback: compiler orders via lgkmcnt, no barrier needed
  {
    int qr = lane >> 1, chh = lane & 1;
    const float* rp = &sm.oep[w][qr][chh * 32];
    const size_t base = (size_t)(qrow0 + w * 32 + qr) * D_MODEL + h * HD + chh * 32;
#pragma unroll
    for (int j = 0; j < 8; ++j) {
      float4 v = *(const float4*)(rp + j * 4);
      f16x4 o;
      o[0] = (_Float16)v.x; o[1] = (_Float16)v.y;
      o[2] = (_Float16)v.z; o[3] = (_Float16)v.w;
      *(f16x4*)(Of + base + j * 4) = o;
    }
  }
}

// ---------------------------------------------------------------------------
// Workspace layout (bytes):
//  [0,8M)    xf16   -> later Of16 (attn output)
//  [8M,10M)  wqf  [10,12) wkf  [12,14) wvf  [14,16) wof
//  [16M,24M) Qb (bf16)  [24,32) Kb  [32,40) Vb  [40,48) Vt
// ---------------------------------------------------------------------------
extern "C" void kernel_launch(void* const* d_in, const int* in_sizes, int n_in,
                              void* d_out, int out_size, void* d_ws, size_t ws_size,
                              hipStream_t stream) {
  const float* x   = (const float*)d_in[0];
  const int*   pos = (const int*)d_in[1];
  const float* Wq  = (const float*)d_in[2];
  const float* Wk  = (const float*)d_in[3];
  const float* Wv  = (const float*)d_in[4];
  const float* Wo  = (const float*)d_in[5];
  float* out = (float*)d_out;

  char* ws = (char*)d_ws;
  const size_t MB = 1024 * 1024;
  _Float16* xf  = (_Float16*)(ws);
  _Float16* wqf = (_Float16*)(ws + 8 * MB);
  _Float16* wkf = (_Float16*)(ws + 10 * MB);
  _Float16* wvf = (_Float16*)(ws + 12 * MB);
  _Float16* wof = (_Float16*)(ws + 14 * MB);
  unsigned short* Qb = (unsigned short*)(ws + 16 * MB);
  unsigned short* Kb = (unsigned short*)(ws + 24 * MB);
  unsigned short* Vb = (unsigned short*)(ws + 32 * MB);
  unsigned short* Vt = (unsigned short*)(ws + 40 * MB);
  _Float16* Of = xf;   // x dead after qkv_gemm

  dim3 blk(256);

  // fp16 conversions
  hipLaunchKernelGGL(cvt_f16, dim3(2048), blk, 0, stream, x, xf,
                     (int)((size_t)S_LEN * D_MODEL / 4));
  hipLaunchKernelGGL(cvt4_f16, dim3(512, 4), blk, 0, stream,
                     Wq, Wk, Wv, Wo, wqf, wkf, wvf, wof,
                     D_MODEL * D_MODEL / 4);

  // fused QKV projection + RoPE (Q scaled by log2e/8), bf16 outputs
  hipLaunchKernelGGL(qkv_gemm, dim3(24, 32), blk, 0, stream,
                     xf, wqf, wkf, wvf, Qb, Kb, Vb, pos);

  // V transpose for conflict-free attention staging
  hipLaunchKernelGGL(vtrans, dim3(64, 16), blk, 0, stream, Vb, Vt);

  // flash attention (writes fp16 O into xf region)
  hipLaunchKernelGGL(attn_mfma, dim3(512), blk, 0, stream, Qb, Kb, Vt, Of);

  // output projection, fp32 to d_out
  hipLaunchKernelGGL(out_gemm, dim3(8, 32), blk, 0, stream, Of, wof, out);
}